// Round 4
// baseline (453.807 us; speedup 1.0000x reference)
//
#include <hip/hip_runtime.h>
#include <cstdint>

#define S_LEN 2048
#define NBATCH 2
#define NHEAD 16
#define E3 3072
#define EDIM 1024
#define DDIM 1024

typedef __attribute__((ext_vector_type(8))) short bf8;
typedef __attribute__((ext_vector_type(8))) unsigned short u16x8;
typedef __attribute__((ext_vector_type(4))) float f4;

#define MFMA16(A, B, C) __builtin_amdgcn_mfma_f32_16x16x32_bf16(A, B, C, 0, 0, 0)

__device__ __forceinline__ ushort bf16rn(float f) {
    unsigned u = __builtin_bit_cast(unsigned, f);
    return (ushort)((u + 0x7fffu + ((u >> 16) & 1u)) >> 16);
}
__device__ __forceinline__ void split2(float f, ushort& h, ushort& l) {
    h = bf16rn(f);
    float hf = __builtin_bit_cast(float, ((unsigned)h) << 16);
    l = bf16rn(f - hf);
}

// ---------------------------------------------------------------------------
// Prep 1: split f32 plane -> hi/lo bf16 planes (vectorized).
// ---------------------------------------------------------------------------
__global__ __launch_bounds__(256) void split_plane(
    const float* __restrict__ X, ushort* __restrict__ Xh, ushort* __restrict__ Xl, int n)
{
    const int i = (blockIdx.x * 256 + threadIdx.x) * 4;
    if (i >= n) return;
    float4 v = *(const float4*)&X[i];
    ushort4 h, l;
    split2(v.x, h.x, l.x); split2(v.y, h.y, l.y);
    split2(v.z, h.z, l.z); split2(v.w, h.w, l.w);
    *(ushort4*)&Xh[i] = h;
    *(ushort4*)&Xl[i] = l;
}

// ---------------------------------------------------------------------------
// Prep 2: W [K][N] f32 -> transposed split planes [N][K] bf16 hi/lo.
// 32x32 LDS tile transpose.
// ---------------------------------------------------------------------------
__global__ __launch_bounds__(256) void transpose_split(
    const float* __restrict__ W, ushort* __restrict__ Th, ushort* __restrict__ Tl,
    int K, int N)
{
    __shared__ float tile[32][33];
    const int t  = threadIdx.x;
    const int n0 = blockIdx.x << 5, k0 = blockIdx.y << 5;
    const int c  = t & 31, r = t >> 5;   // r in [0,8)
    #pragma unroll
    for (int i = 0; i < 4; ++i)
        tile[c][r + (i << 3)] = W[(size_t)(k0 + r + (i << 3)) * N + n0 + c];
    __syncthreads();
    #pragma unroll
    for (int i = 0; i < 4; ++i) {
        float v = tile[r + (i << 3)][c];
        ushort hh, ll; split2(v, hh, ll);
        Th[(size_t)(n0 + r + (i << 3)) * K + k0 + c] = hh;
        Tl[(size_t)(n0 + r + (i << 3)) * K + k0 + c] = ll;
    }
}

// ---------------------------------------------------------------------------
// MFMA GEMM, bf16x3, all inputs pre-split: A planes [M][K], B planes [N][K].
// Inner loop: pure {global 16B loads (A), ds_read_b128 (B), MFMA}.
// MODE 0: C -> split hi/lo planes (bias; Q cols (c%192<64) scaled 0.125).
// MODE 1: C -> f32 (bias).
// ---------------------------------------------------------------------------
template<int MODE>
__global__ __launch_bounds__(256) void gemm_planes(
    const ushort* __restrict__ Ah, const ushort* __restrict__ Al,
    const ushort* __restrict__ Bh, const ushort* __restrict__ Bl,
    const float* __restrict__ bias,
    float* __restrict__ Cf, ushort* __restrict__ Ch, ushort* __restrict__ Cl,
    int M, int N, int K)
{
    __shared__ ushort bsh[64][72];
    __shared__ ushort bsl[64][72];

    const int t    = threadIdx.x;
    const int lane = t & 63;
    const int wv   = t >> 6;
    const int lo   = lane & 15, hi = lane >> 4;
    const int rb   = (blockIdx.y << 6) + (wv << 4);
    const int cb   = blockIdx.x << 6;
    const int sn   = t >> 2, sk = (t & 3) << 4;   // staging: 16 ushorts per thread

    f4 acc[4] = {};

    for (int k0 = 0; k0 < K; k0 += 64) {
        __syncthreads();
        {
            const size_t g = (size_t)(cb + sn) * K + k0 + sk;
            *(u16x8*)&bsh[sn][sk]     = *(const u16x8*)&Bh[g];
            *(u16x8*)&bsh[sn][sk + 8] = *(const u16x8*)&Bh[g + 8];
            *(u16x8*)&bsl[sn][sk]     = *(const u16x8*)&Bl[g];
            *(u16x8*)&bsl[sn][sk + 8] = *(const u16x8*)&Bl[g + 8];
        }
        __syncthreads();

        #pragma unroll
        for (int kk = 0; kk < 2; ++kk) {
            const size_t aoff = (size_t)(rb + lo) * K + k0 + (kk << 5) + (hi << 3);
            bf8 ah = *(const bf8*)&Ah[aoff];
            bf8 al = *(const bf8*)&Al[aoff];
            #pragma unroll
            for (int ct = 0; ct < 4; ++ct) {
                bf8 bh = *(const bf8*)&bsh[(ct << 4) + lo][(kk << 5) + (hi << 3)];
                bf8 bl = *(const bf8*)&bsl[(ct << 4) + lo][(kk << 5) + (hi << 3)];
                acc[ct] = MFMA16(ah, bh, acc[ct]);
                acc[ct] = MFMA16(ah, bl, acc[ct]);
                acc[ct] = MFMA16(al, bh, acc[ct]);
            }
        }
    }

    #pragma unroll
    for (int ct = 0; ct < 4; ++ct) {
        const int c  = cb + (ct << 4) + lo;
        const float bv = bias[c];
        const float qs = (MODE == 0 && (c % 192) < 64) ? 0.125f : 1.0f;
        #pragma unroll
        for (int j = 0; j < 4; ++j) {
            const size_t row = (size_t)rb + (hi << 2) + j;
            float v = (acc[ct][j] + bv) * qs;
            if (MODE == 0) {
                ushort hh, ll; split2(v, hh, ll);
                Ch[row * N + c] = hh;
                Cl[row * N + c] = ll;
            } else {
                Cf[row * N + c] = v;
            }
        }
    }
}

// ---------------------------------------------------------------------------
// Fused attention v3: 8 waves x 16 q-rows = 128 q-rows/block.
// Swapped QK^T (A=K, B=Q): D = [k][q] -> float4 attn stores, 2-shfl row sums.
// Double-buffered K (and V in pass 2) with reg-staged prefetch (T14):
//   per tile: B1 -> issue next-tile global loads, compute current -> B2 ->
//   ds_write next tile into alternate buffer.  setprio(1) around MFMA (T5).
// ---------------------------------------------------------------------------
__global__ __launch_bounds__(512) void attn_fused(
    const ushort* __restrict__ qh, const ushort* __restrict__ ql,
    float* __restrict__ attn, ushort* __restrict__ oh, ushort* __restrict__ ol)
{
    __shared__ ushort ksh_h[2][64][72];
    __shared__ ushort ksh_l[2][64][72];
    __shared__ ushort vth[2][64][72];     // V^T: [d][k]
    __shared__ ushort plds[8][16][72];    // per-wave p: [q][k]

    const int t    = threadIdx.x;
    const int lane = t & 63;
    const int wv   = t >> 6;
    const int lo   = lane & 15, hi = lane >> 4;
    const int bh   = blockIdx.y;
    const int b    = bh >> 4, h = bh & 15;
    const size_t base = (size_t)b * S_LEN * E3 + h * 192;
    const int q0   = (blockIdx.x << 7) + (wv << 4);

    const int srow = t >> 4, sc4 = (t & 15) << 2;   // K staging coords
    const int vd   = t & 63;                        // V staging coords

    // Q fragments in registers
    bf8 qfh[2], qfl[2];
    #pragma unroll
    for (int st = 0; st < 2; ++st) {
        const size_t off = base + (size_t)(q0 + lo) * E3 + (st << 5) + (hi << 3);
        qfh[st] = *(const bf8*)&qh[off];
        qfl[st] = *(const bf8*)&ql[off];
    }

    ushort4 krh[2], krl[2], vr[2];

    auto loadK = [&](int kt) {
        #pragma unroll
        for (int i = 0; i < 2; ++i) {
            const size_t g = base + 64 + (size_t)(kt + srow + (i << 5)) * E3 + sc4;
            krh[i] = *(const ushort4*)&qh[g];
            krl[i] = *(const ushort4*)&ql[g];
        }
    };
    auto writeK = [&](int buf) {
        #pragma unroll
        for (int i = 0; i < 2; ++i) {
            *(ushort4*)&ksh_h[buf][srow + (i << 5)][sc4] = krh[i];
            *(ushort4*)&ksh_l[buf][srow + (i << 5)][sc4] = krl[i];
        }
    };
    auto loadV = [&](int kt) {
        #pragma unroll
        for (int i = 0; i < 2; ++i) {
            const int k4 = ((t >> 6) + (i << 3)) << 2;
            ushort4 v;
            #pragma unroll
            for (int m = 0; m < 4; ++m)
                ((ushort*)&v)[m] = qh[base + 128 + (size_t)(kt + k4 + m) * E3 + vd];
            vr[i] = v;
        }
    };
    auto writeV = [&](int buf) {
        #pragma unroll
        for (int i = 0; i < 2; ++i)
            *(ushort4*)&vth[buf][vd][((t >> 6) + (i << 3)) << 2] = vr[i];
    };

    // ---- pass 1: denominators
    loadK(0); writeK(0);
    float ssum = 0.0f;
    for (int kt = 0; kt < S_LEN; kt += 64) {
        const int buf = (kt >> 6) & 1;
        __syncthreads();
        const bool pf = (kt + 64 < S_LEN);
        if (pf) loadK(kt + 64);
        __builtin_amdgcn_s_setprio(1);
        #pragma unroll
        for (int sub = 0; sub < 4; ++sub) {
            f4 acc = {};
            #pragma unroll
            for (int st = 0; st < 2; ++st) {
                bf8 kh = *(const bf8*)&ksh_h[buf][(sub << 4) + lo][(st << 5) + (hi << 3)];
                bf8 kl = *(const bf8*)&ksh_l[buf][(sub << 4) + lo][(st << 5) + (hi << 3)];
                acc = MFMA16(kh, qfh[st], acc);
                acc = MFMA16(kh, qfl[st], acc);
                acc = MFMA16(kl, qfh[st], acc);
            }
            #pragma unroll
            for (int j = 0; j < 4; ++j) ssum += __expf(acc[j]);
        }
        __builtin_amdgcn_s_setprio(0);
        __syncthreads();
        if (pf) writeK(buf ^ 1);
    }
    ssum += __shfl_xor(ssum, 16, 64);
    ssum += __shfl_xor(ssum, 32, 64);
    const float inv_s = 1.0f / ssum;

    // ---- pass 2: attention write + PV
    loadK(0); loadV(0); writeK(0); writeV(0);
    f4 oacc[4] = {};
    for (int kt = 0; kt < S_LEN; kt += 64) {
        const int buf = (kt >> 6) & 1;
        __syncthreads();
        const bool pf = (kt + 64 < S_LEN);
        if (pf) { loadK(kt + 64); loadV(kt + 64); }

        __builtin_amdgcn_s_setprio(1);
        #pragma unroll
        for (int sub = 0; sub < 4; ++sub) {
            f4 acc = {};
            #pragma unroll
            for (int st = 0; st < 2; ++st) {
                bf8 kh = *(const bf8*)&ksh_h[buf][(sub << 4) + lo][(st << 5) + (hi << 3)];
                bf8 kl = *(const bf8*)&ksh_l[buf][(sub << 4) + lo][(st << 5) + (hi << 3)];
                acc = MFMA16(kh, qfh[st], acc);
                acc = MFMA16(kh, qfl[st], acc);
                acc = MFMA16(kl, qfh[st], acc);
            }
            __builtin_amdgcn_s_setprio(0);
            float4 pw; ushort4 pb;
            #pragma unroll
            for (int j = 0; j < 4; ++j) {
                float p = __expf(acc[j]) * inv_s;
                ((float*)&pw)[j] = p;
                ((ushort*)&pb)[j] = bf16rn(p);
            }
            *(float4*)&attn[((size_t)bh * S_LEN + q0 + lo) * S_LEN +
                            kt + (sub << 4) + (hi << 2)] = pw;
            *(ushort4*)&plds[wv][lo][(sub << 4) + (hi << 2)] = pb;
            __builtin_amdgcn_s_setprio(1);
        }
        // PV: o += p @ V
        #pragma unroll
        for (int kk = 0; kk < 2; ++kk) {
            bf8 pa = *(const bf8*)&plds[wv][lo][(kk << 5) + (hi << 3)];
            #pragma unroll
            for (int dt = 0; dt < 4; ++dt) {
                bf8 vb = *(const bf8*)&vth[buf][(dt << 4) + lo][(kk << 5) + (hi << 3)];
                oacc[dt] = MFMA16(pa, vb, oacc[dt]);
            }
        }
        __builtin_amdgcn_s_setprio(0);
        __syncthreads();
        if (pf) { writeK(buf ^ 1); writeV(buf ^ 1); }
    }

    // epilogue: split o head planes for out-proj GEMM
    #pragma unroll
    for (int dt = 0; dt < 4; ++dt) {
        #pragma unroll
        for (int j = 0; j < 4; ++j) {
            const size_t row = (size_t)b * S_LEN + q0 + (hi << 2) + j;
            ushort hh, ll; split2(oacc[dt][j], hh, ll);
            oh[row * EDIM + h * 64 + (dt << 4) + lo] = hh;
            ol[row * EDIM + h * 64 + (dt << 4) + lo] = ll;
        }
    }
}

// ---------------------------------------------------------------------------
extern "C" void kernel_launch(void* const* d_in, const int* in_sizes, int n_in,
                              void* d_out, int out_size, void* d_ws, size_t ws_size,
                              hipStream_t stream)
{
    const float* x    = (const float*)d_in[0];
    const float* Wqkv = (const float*)d_in[1];
    const float* bqkv = (const float*)d_in[2];
    const float* Wout = (const float*)d_in[3];
    const float* bout = (const float*)d_in[4];

    float* o_out    = (float*)d_out;
    float* attn_out = o_out + (size_t)NBATCH * S_LEN * DDIM;

    const size_t nQKV = (size_t)NBATCH * S_LEN * E3;    // 12.58M
    const size_t nO   = (size_t)NBATCH * S_LEN * EDIM;  // 4.19M
    const size_t nWq  = (size_t)DDIM * E3;              // 3.15M
    const size_t nWo  = (size_t)EDIM * DDIM;            // 1.05M

    ushort* qh    = (ushort*)d_ws;
    ushort* ql    = qh + nQKV;
    ushort* oh    = ql + nQKV;      // doubles as xh before attn
    ushort* ol    = oh + nO;        // doubles as xl before attn
    ushort* wqt_h = ol + nO;
    ushort* wqt_l = wqt_h + nWq;
    ushort* wot_h = wqt_l + nWq;
    ushort* wot_l = wot_h + nWo;

    ushort* xh = oh;  // overlay: x planes dead after gemm1
    ushort* xl = ol;

    const int M = NBATCH * S_LEN;  // 4096

    // prep: split x; transpose+split weights
    split_plane<<<(int)(nO / 1024), 256, 0, stream>>>(x, xh, xl, (int)nO);
    transpose_split<<<dim3(E3 / 32, DDIM / 32), 256, 0, stream>>>(Wqkv, wqt_h, wqt_l, DDIM, E3);
    transpose_split<<<dim3(DDIM / 32, EDIM / 32), 256, 0, stream>>>(Wout, wot_h, wot_l, EDIM, DDIM);

    // K1: qkv = x @ Wqkv + bqkv -> split planes (Q pre-scaled 0.125)
    gemm_planes<0><<<dim3(E3 / 64, M / 64), 256, 0, stream>>>(
        xh, xl, wqt_h, wqt_l, bqkv, nullptr, qh, ql, M, E3, DDIM);

    // K2: fused attention
    attn_fused<<<dim3(S_LEN / 128, NBATCH * NHEAD), 512, 0, stream>>>(
        qh, ql, attn_out, oh, ol);

    // K3: o = o_head @ Wout + bout
    gemm_planes<1><<<dim3(DDIM / 64, M / 64), 256, 0, stream>>>(
        oh, ol, wot_h, wot_l, bout, o_out, nullptr, nullptr, M, DDIM, EDIM);
}

// Round 5
// 422.961 us; speedup vs baseline: 1.0729x; 1.0729x over previous
//
#include <hip/hip_runtime.h>
#include <cstdint>

#define S_LEN 2048
#define NBATCH 2
#define NHEAD 16
#define E3 3072
#define EDIM 1024
#define DDIM 1024

typedef __attribute__((ext_vector_type(8))) short bf8;
typedef __attribute__((ext_vector_type(8))) unsigned short u16x8;
typedef __attribute__((ext_vector_type(4))) float f4;

#define MFMA16(A, B, C) __builtin_amdgcn_mfma_f32_16x16x32_bf16(A, B, C, 0, 0, 0)

__device__ __forceinline__ ushort bf16rn(float f) {
    unsigned u = __builtin_bit_cast(unsigned, f);
    return (ushort)((u + 0x7fffu + ((u >> 16) & 1u)) >> 16);
}
__device__ __forceinline__ void split2(float f, ushort& h, ushort& l) {
    h = bf16rn(f);
    float hf = __builtin_bit_cast(float, ((unsigned)h) << 16);
    l = bf16rn(f - hf);
}

// ---------------------------------------------------------------------------
// Prep 1: split f32 plane -> hi/lo bf16 planes.
// ---------------------------------------------------------------------------
__global__ __launch_bounds__(256) void split_plane(
    const float* __restrict__ X, ushort* __restrict__ Xh, ushort* __restrict__ Xl, int n)
{
    const int i = (blockIdx.x * 256 + threadIdx.x) * 4;
    if (i >= n) return;
    float4 v = *(const float4*)&X[i];
    ushort4 h, l;
    split2(v.x, h.x, l.x); split2(v.y, h.y, l.y);
    split2(v.z, h.z, l.z); split2(v.w, h.w, l.w);
    *(ushort4*)&Xh[i] = h;
    *(ushort4*)&Xl[i] = l;
}

// ---------------------------------------------------------------------------
// Prep 2: W [K][N] f32 -> transposed split planes [N][K] bf16 hi/lo.
// ---------------------------------------------------------------------------
__global__ __launch_bounds__(256) void transpose_split(
    const float* __restrict__ W, ushort* __restrict__ Th, ushort* __restrict__ Tl,
    int K, int N)
{
    __shared__ float tile[32][33];
    const int t  = threadIdx.x;
    const int n0 = blockIdx.x << 5, k0 = blockIdx.y << 5;
    const int c  = t & 31, r = t >> 5;
    #pragma unroll
    for (int i = 0; i < 4; ++i)
        tile[c][r + (i << 3)] = W[(size_t)(k0 + r + (i << 3)) * N + n0 + c];
    __syncthreads();
    #pragma unroll
    for (int i = 0; i < 4; ++i) {
        float v = tile[r + (i << 3)][c];
        ushort hh, ll; split2(v, hh, ll);
        Th[(size_t)(n0 + r + (i << 3)) * K + k0 + c] = hh;
        Tl[(size_t)(n0 + r + (i << 3)) * K + k0 + c] = ll;
    }
}

// ---------------------------------------------------------------------------
// MFMA GEMM, bf16x3, 128x128 tile, BK=64, 512 thr = 8 waves (2x4 of 64x32).
// A planes [M][K], B planes [N][K] (pre-transposed). Padded LDS [128][72]:
// frag ds_read_b128 and staging ds_write_b128 both at LDS BW minimum.
// MODE 0: C -> split planes (bias; Q cols (c%192<64) scaled 0.125).
// MODE 1: C -> f32 (bias).
// ---------------------------------------------------------------------------
template<int MODE>
__global__ __launch_bounds__(512, 4) void gemm_planes(
    const ushort* __restrict__ Ah, const ushort* __restrict__ Al,
    const ushort* __restrict__ Bh, const ushort* __restrict__ Bl,
    const float* __restrict__ bias,
    float* __restrict__ Cf, ushort* __restrict__ Ch, ushort* __restrict__ Cl,
    int M, int N, int K)
{
    __shared__ ushort As_h[128][72];
    __shared__ ushort As_l[128][72];
    __shared__ ushort Bs_h[128][72];
    __shared__ ushort Bs_l[128][72];

    const int t    = threadIdx.x;
    const int lane = t & 63;
    const int w    = t >> 6;
    const int lo   = lane & 15, hi = lane >> 4;
    const int wr   = w >> 2;          // 0..1 -> row block of 64
    const int wc   = w & 3;           // 0..3 -> col block of 32
    const int rb   = blockIdx.y << 7;
    const int cb   = blockIdx.x << 7;

    const int srow = t >> 3;          // 0..63
    const int sc   = (t & 7) << 3;    // ushort col: 0,8,...,56

    f4 acc[4][2] = {};

    for (int k0 = 0; k0 < K; k0 += 64) {
        __syncthreads();
        #pragma unroll
        for (int i = 0; i < 2; ++i) {
            const int r = srow + (i << 6);
            const size_t ga = (size_t)(rb + r) * K + k0 + sc;
            const size_t gb = (size_t)(cb + r) * K + k0 + sc;
            *(u16x8*)&As_h[r][sc] = *(const u16x8*)&Ah[ga];
            *(u16x8*)&As_l[r][sc] = *(const u16x8*)&Al[ga];
            *(u16x8*)&Bs_h[r][sc] = *(const u16x8*)&Bh[gb];
            *(u16x8*)&Bs_l[r][sc] = *(const u16x8*)&Bl[gb];
        }
        __syncthreads();

        __builtin_amdgcn_s_setprio(1);
        #pragma unroll
        for (int st = 0; st < 2; ++st) {
            const int kcol = (st << 5) + (hi << 3);
            bf8 a_h[4], a_l[4], b_h[2], b_l[2];
            #pragma unroll
            for (int f = 0; f < 4; ++f) {
                const int r = (wr << 6) + (f << 4) + lo;
                a_h[f] = *(const bf8*)&As_h[r][kcol];
                a_l[f] = *(const bf8*)&As_l[r][kcol];
            }
            #pragma unroll
            for (int g = 0; g < 2; ++g) {
                const int c = (wc << 5) + (g << 4) + lo;
                b_h[g] = *(const bf8*)&Bs_h[c][kcol];
                b_l[g] = *(const bf8*)&Bs_l[c][kcol];
            }
            #pragma unroll
            for (int f = 0; f < 4; ++f)
                #pragma unroll
                for (int g = 0; g < 2; ++g) {
                    acc[f][g] = MFMA16(a_h[f], b_h[g], acc[f][g]);
                    acc[f][g] = MFMA16(a_h[f], b_l[g], acc[f][g]);
                    acc[f][g] = MFMA16(a_l[f], b_h[g], acc[f][g]);
                }
        }
        __builtin_amdgcn_s_setprio(0);
    }

    #pragma unroll
    for (int f = 0; f < 4; ++f) {
        #pragma unroll
        for (int g = 0; g < 2; ++g) {
            const int c  = cb + (wc << 5) + (g << 4) + lo;
            const float bv = bias[c];
            const float qs = (MODE == 0 && (c % 192) < 64) ? 0.125f : 1.0f;
            #pragma unroll
            for (int j = 0; j < 4; ++j) {
                const size_t row = (size_t)rb + (wr << 6) + (f << 4) + (hi << 2) + j;
                float v = (acc[f][g][j] + bv) * qs;
                if (MODE == 0) {
                    ushort hh, ll; split2(v, hh, ll);
                    Ch[row * N + c] = hh;
                    Cl[row * N + c] = ll;
                } else {
                    Cf[row * N + c] = v;
                }
            }
        }
    }
}

// ---------------------------------------------------------------------------
// Fused attention (round-3 structure: single-buffered, 46KB LDS, 3 blocks/CU)
// + s_setprio around MFMA clusters. 8 waves x 16 q-rows = 128 q-rows/block.
// Swapped QK^T (A=K, B=Q): D=[k][q] -> float4 attn stores, 2-shfl row sums.
// ---------------------------------------------------------------------------
__global__ __launch_bounds__(512) void attn_fused(
    const ushort* __restrict__ qh, const ushort* __restrict__ ql,
    float* __restrict__ attn, ushort* __restrict__ oh, ushort* __restrict__ ol)
{
    __shared__ ushort ksh_h[64][72];
    __shared__ ushort ksh_l[64][72];
    __shared__ ushort vth[64][72];       // V^T: [d][k]
    __shared__ ushort plds[8][16][72];   // per-wave p: [q][k]

    const int t    = threadIdx.x;
    const int lane = t & 63;
    const int wv   = t >> 6;
    const int lo   = lane & 15, hi = lane >> 4;
    const int bh   = blockIdx.y;
    const int b    = bh >> 4, h = bh & 15;
    const size_t base = (size_t)b * S_LEN * E3 + h * 192;
    const int q0   = (blockIdx.x << 7) + (wv << 4);

    bf8 qfh[2], qfl[2];
    #pragma unroll
    for (int st = 0; st < 2; ++st) {
        const size_t off = base + (size_t)(q0 + lo) * E3 + (st << 5) + (hi << 3);
        qfh[st] = *(const bf8*)&qh[off];
        qfl[st] = *(const bf8*)&ql[off];
    }

    // ---- pass 1: denominators
    float ssum = 0.0f;
    for (int kt = 0; kt < S_LEN; kt += 64) {
        __syncthreads();
        #pragma unroll
        for (int i = 0; i < 2; ++i) {
            const int idx = t + (i << 9);
            const int row = idx >> 4, c4 = (idx & 15) << 2;
            const size_t g = base + 64 + (size_t)(kt + row) * E3 + c4;
            *(ushort4*)&ksh_h[row][c4] = *(const ushort4*)&qh[g];
            *(ushort4*)&ksh_l[row][c4] = *(const ushort4*)&ql[g];
        }
        __syncthreads();
        __builtin_amdgcn_s_setprio(1);
        #pragma unroll
        for (int sub = 0; sub < 4; ++sub) {
            f4 acc = {};
            #pragma unroll
            for (int st = 0; st < 2; ++st) {
                bf8 kh = *(const bf8*)&ksh_h[(sub << 4) + lo][(st << 5) + (hi << 3)];
                bf8 kl = *(const bf8*)&ksh_l[(sub << 4) + lo][(st << 5) + (hi << 3)];
                acc = MFMA16(kh, qfh[st], acc);
                acc = MFMA16(kh, qfl[st], acc);
                acc = MFMA16(kl, qfh[st], acc);
            }
            #pragma unroll
            for (int j = 0; j < 4; ++j) ssum += __expf(acc[j]);
        }
        __builtin_amdgcn_s_setprio(0);
    }
    ssum += __shfl_xor(ssum, 16, 64);
    ssum += __shfl_xor(ssum, 32, 64);
    const float inv_s = 1.0f / ssum;

    // ---- pass 2: attention write + PV
    f4 oacc[4] = {};
    for (int kt = 0; kt < S_LEN; kt += 64) {
        __syncthreads();
        #pragma unroll
        for (int i = 0; i < 2; ++i) {   // stage K
            const int idx = t + (i << 9);
            const int row = idx >> 4, c4 = (idx & 15) << 2;
            const size_t g = base + 64 + (size_t)(kt + row) * E3 + c4;
            *(ushort4*)&ksh_h[row][c4] = *(const ushort4*)&qh[g];
            *(ushort4*)&ksh_l[row][c4] = *(const ushort4*)&ql[g];
        }
        #pragma unroll
        for (int i = 0; i < 2; ++i) {   // stage V^T
            const int d = t & 63;
            const int k4 = ((t >> 6) + (i << 3)) << 2;
            ushort4 v;
            #pragma unroll
            for (int m = 0; m < 4; ++m)
                ((ushort*)&v)[m] = qh[base + 128 + (size_t)(kt + k4 + m) * E3 + d];
            *(ushort4*)&vth[d][k4] = v;
        }
        __syncthreads();

        #pragma unroll
        for (int sub = 0; sub < 4; ++sub) {
            f4 acc = {};
            __builtin_amdgcn_s_setprio(1);
            #pragma unroll
            for (int st = 0; st < 2; ++st) {
                bf8 kh = *(const bf8*)&ksh_h[(sub << 4) + lo][(st << 5) + (hi << 3)];
                bf8 kl = *(const bf8*)&ksh_l[(sub << 4) + lo][(st << 5) + (hi << 3)];
                acc = MFMA16(kh, qfh[st], acc);
                acc = MFMA16(kh, qfl[st], acc);
                acc = MFMA16(kl, qfh[st], acc);
            }
            __builtin_amdgcn_s_setprio(0);
            float4 pw; ushort4 pb;
            #pragma unroll
            for (int j = 0; j < 4; ++j) {
                float p = __expf(acc[j]) * inv_s;
                ((float*)&pw)[j] = p;
                ((ushort*)&pb)[j] = bf16rn(p);
            }
            *(float4*)&attn[((size_t)bh * S_LEN + q0 + lo) * S_LEN +
                            kt + (sub << 4) + (hi << 2)] = pw;
            *(ushort4*)&plds[wv][lo][(sub << 4) + (hi << 2)] = pb;
        }
        // PV: o += p @ V
        __builtin_amdgcn_s_setprio(1);
        #pragma unroll
        for (int kk = 0; kk < 2; ++kk) {
            bf8 pa = *(const bf8*)&plds[wv][lo][(kk << 5) + (hi << 3)];
            #pragma unroll
            for (int dt = 0; dt < 4; ++dt) {
                bf8 vb = *(const bf8*)&vth[(dt << 4) + lo][(kk << 5) + (hi << 3)];
                oacc[dt] = MFMA16(pa, vb, oacc[dt]);
            }
        }
        __builtin_amdgcn_s_setprio(0);
    }

    // epilogue: split o head planes for out-proj GEMM
    #pragma unroll
    for (int dt = 0; dt < 4; ++dt) {
        #pragma unroll
        for (int j = 0; j < 4; ++j) {
            const size_t row = (size_t)b * S_LEN + q0 + (hi << 2) + j;
            ushort hh, ll; split2(oacc[dt][j], hh, ll);
            oh[row * EDIM + h * 64 + (dt << 4) + lo] = hh;
            ol[row * EDIM + h * 64 + (dt << 4) + lo] = ll;
        }
    }
}

// ---------------------------------------------------------------------------
extern "C" void kernel_launch(void* const* d_in, const int* in_sizes, int n_in,
                              void* d_out, int out_size, void* d_ws, size_t ws_size,
                              hipStream_t stream)
{
    const float* x    = (const float*)d_in[0];
    const float* Wqkv = (const float*)d_in[1];
    const float* bqkv = (const float*)d_in[2];
    const float* Wout = (const float*)d_in[3];
    const float* bout = (const float*)d_in[4];

    float* o_out    = (float*)d_out;
    float* attn_out = o_out + (size_t)NBATCH * S_LEN * DDIM;

    const size_t nQKV = (size_t)NBATCH * S_LEN * E3;
    const size_t nO   = (size_t)NBATCH * S_LEN * EDIM;
    const size_t nWq  = (size_t)DDIM * E3;
    const size_t nWo  = (size_t)EDIM * DDIM;

    ushort* qh    = (ushort*)d_ws;
    ushort* ql    = qh + nQKV;
    ushort* oh    = ql + nQKV;      // doubles as xh before attn
    ushort* ol    = oh + nO;        // doubles as xl before attn
    ushort* wqt_h = ol + nO;
    ushort* wqt_l = wqt_h + nWq;
    ushort* wot_h = wqt_l + nWq;
    ushort* wot_l = wot_h + nWo;

    ushort* xh = oh;
    ushort* xl = ol;

    const int M = NBATCH * S_LEN;  // 4096

    split_plane<<<(int)(nO / 1024), 256, 0, stream>>>(x, xh, xl, (int)nO);
    transpose_split<<<dim3(E3 / 32, DDIM / 32), 256, 0, stream>>>(Wqkv, wqt_h, wqt_l, DDIM, E3);
    transpose_split<<<dim3(DDIM / 32, EDIM / 32), 256, 0, stream>>>(Wout, wot_h, wot_l, EDIM, DDIM);

    gemm_planes<0><<<dim3(E3 / 128, M / 128), 512, 0, stream>>>(
        xh, xl, wqt_h, wqt_l, bqkv, nullptr, qh, ql, M, E3, DDIM);

    attn_fused<<<dim3(S_LEN / 128, NBATCH * NHEAD), 512, 0, stream>>>(
        qh, ql, attn_out, oh, ol);

    gemm_planes<1><<<dim3(DDIM / 128, M / 128), 512, 0, stream>>>(
        oh, ol, wot_h, wot_l, bout, o_out, nullptr, nullptr, M, DDIM, EDIM);
}

// Round 6
// 416.848 us; speedup vs baseline: 1.0887x; 1.0147x over previous
//
#include <hip/hip_runtime.h>
#include <cstdint>

#define S_LEN 2048
#define NBATCH 2
#define NHEAD 16
#define E3 3072
#define EDIM 1024
#define DDIM 1024

typedef __attribute__((ext_vector_type(8))) short bf8;
typedef __attribute__((ext_vector_type(4))) float f4;

#define MFMA16(A, B, C) __builtin_amdgcn_mfma_f32_16x16x32_bf16(A, B, C, 0, 0, 0)

__device__ __forceinline__ ushort bf16rn(float f) {
    unsigned u = __builtin_bit_cast(unsigned, f);
    return (ushort)((u + 0x7fffu + ((u >> 16) & 1u)) >> 16);
}
__device__ __forceinline__ void split2(float f, ushort& h, ushort& l) {
    h = bf16rn(f);
    float hf = __builtin_bit_cast(float, ((unsigned)h) << 16);
    l = bf16rn(f - hf);
}

// global -> LDS direct DMA, 16B per lane. LDS dest = wave-uniform base +
// lane*16 (linear). Swizzle is applied on the GLOBAL source address and on
// the LDS reads (rule #21: both-sides-or-neither).
__device__ __forceinline__ void gload_lds16(const ushort* g, ushort* l) {
    __builtin_amdgcn_global_load_lds(
        (const __attribute__((address_space(1))) void*)g,
        (__attribute__((address_space(3))) void*)l, 16, 0, 0);
}

// ---------------------------------------------------------------------------
// Prep 1: split f32 plane -> hi/lo bf16 planes.
// ---------------------------------------------------------------------------
__global__ __launch_bounds__(256) void split_plane(
    const float* __restrict__ X, ushort* __restrict__ Xh, ushort* __restrict__ Xl, int n)
{
    const int i = (blockIdx.x * 256 + threadIdx.x) * 4;
    if (i >= n) return;
    float4 v = *(const float4*)&X[i];
    ushort4 h, l;
    split2(v.x, h.x, l.x); split2(v.y, h.y, l.y);
    split2(v.z, h.z, l.z); split2(v.w, h.w, l.w);
    *(ushort4*)&Xh[i] = h;
    *(ushort4*)&Xl[i] = l;
}

// ---------------------------------------------------------------------------
// Prep 2: W [K][N] f32 -> transposed split planes [N][K] bf16 hi/lo.
// ---------------------------------------------------------------------------
__global__ __launch_bounds__(256) void transpose_split(
    const float* __restrict__ W, ushort* __restrict__ Th, ushort* __restrict__ Tl,
    int K, int N)
{
    __shared__ float tile[32][33];
    const int t  = threadIdx.x;
    const int n0 = blockIdx.x << 5, k0 = blockIdx.y << 5;
    const int c  = t & 31, r = t >> 5;
    #pragma unroll
    for (int i = 0; i < 4; ++i)
        tile[c][r + (i << 3)] = W[(size_t)(k0 + r + (i << 3)) * N + n0 + c];
    __syncthreads();
    #pragma unroll
    for (int i = 0; i < 4; ++i) {
        float v = tile[r + (i << 3)][c];
        ushort hh, ll; split2(v, hh, ll);
        Th[(size_t)(n0 + r + (i << 3)) * K + k0 + c] = hh;
        Tl[(size_t)(n0 + r + (i << 3)) * K + k0 + c] = ll;
    }
}

// ---------------------------------------------------------------------------
// MFMA GEMM, bf16x3, 128x128 tile, BK=64, 512 thr = 8 waves (2x4 of 64x32).
// Staging via global_load_lds (16B/lane) into linear LDS [128][64]; the
// involution col16 ^= (row&7)<<4 is pre-applied to the global source and
// re-applied on fragment reads -> conflict-free ds_read_b128.
// MODE 0: C -> split planes (bias; Q cols (c%192<64) scaled 0.125).
// MODE 1: C -> f32 (bias).
// ---------------------------------------------------------------------------
template<int MODE>
__global__ __launch_bounds__(512, 4) void gemm_planes(
    const ushort* __restrict__ Ah, const ushort* __restrict__ Al,
    const ushort* __restrict__ Bh, const ushort* __restrict__ Bl,
    const float* __restrict__ bias,
    float* __restrict__ Cf, ushort* __restrict__ Ch, ushort* __restrict__ Cl,
    int M, int N, int K)
{
    __shared__ ushort As_h[128][64];
    __shared__ ushort As_l[128][64];
    __shared__ ushort Bs_h[128][64];
    __shared__ ushort Bs_l[128][64];

    const int t    = threadIdx.x;
    const int lane = t & 63;
    const int w    = t >> 6;
    const int lo   = lane & 15, hi = lane >> 4;
    const int wr   = w >> 2;          // 0..1 -> row block of 64
    const int wc   = w & 3;           // 0..3 -> col block of 32
    const int rb   = blockIdx.y << 7;
    const int cb   = blockIdx.x << 7;

    // staging geometry: chunk = 8 rows x 64 ushorts = 1KB = one wave-load
    const int lrow = lane >> 3;                          // row within chunk (== row&7)
    const int scol = ((lane & 7) ^ lrow) << 3;           // pre-swizzled ushort col
    const int w8   = w << 1;                             // wave's chunk pair

    // fragment-read swizzle: row&7 == lo&7 for all fragments
    const int rsw  = (lo & 7) << 3;

    f4 acc[4][2] = {};

    for (int k0 = 0; k0 < K; k0 += 64) {
        __syncthreads();
        #pragma unroll
        for (int i = 0; i < 2; ++i) {
            const int r0  = (w8 + i) << 3;
            const int row = r0 + lrow;
            const size_t ga = (size_t)(rb + row) * K + k0 + scol;
            const size_t gb = (size_t)(cb + row) * K + k0 + scol;
            gload_lds16(&Ah[ga], &As_h[r0][0]);
            gload_lds16(&Al[ga], &As_l[r0][0]);
            gload_lds16(&Bh[gb], &Bs_h[r0][0]);
            gload_lds16(&Bl[gb], &Bs_l[r0][0]);
        }
        __syncthreads();   // drains vmcnt: all LDS writes landed

        __builtin_amdgcn_s_setprio(1);
        #pragma unroll
        for (int st = 0; st < 2; ++st) {
            const int kc = ((st << 5) + (hi << 3)) ^ rsw;
            bf8 a_h[4], a_l[4], b_h[2], b_l[2];
            #pragma unroll
            for (int f = 0; f < 4; ++f) {
                const int r = (wr << 6) + (f << 4) + lo;
                a_h[f] = *(const bf8*)&As_h[r][kc];
                a_l[f] = *(const bf8*)&As_l[r][kc];
            }
            #pragma unroll
            for (int g = 0; g < 2; ++g) {
                const int c = (wc << 5) + (g << 4) + lo;
                b_h[g] = *(const bf8*)&Bs_h[c][kc];
                b_l[g] = *(const bf8*)&Bs_l[c][kc];
            }
            #pragma unroll
            for (int f = 0; f < 4; ++f)
                #pragma unroll
                for (int g = 0; g < 2; ++g) {
                    acc[f][g] = MFMA16(a_h[f], b_h[g], acc[f][g]);
                    acc[f][g] = MFMA16(a_h[f], b_l[g], acc[f][g]);
                    acc[f][g] = MFMA16(a_l[f], b_h[g], acc[f][g]);
                }
        }
        __builtin_amdgcn_s_setprio(0);
    }

    #pragma unroll
    for (int f = 0; f < 4; ++f) {
        #pragma unroll
        for (int g = 0; g < 2; ++g) {
            const int c  = cb + (wc << 5) + (g << 4) + lo;
            const float bv = bias[c];
            const float qs = (MODE == 0 && (c % 192) < 64) ? 0.125f : 1.0f;
            #pragma unroll
            for (int j = 0; j < 4; ++j) {
                const size_t row = (size_t)rb + (wr << 6) + (f << 4) + (hi << 2) + j;
                float v = (acc[f][g][j] + bv) * qs;
                if (MODE == 0) {
                    ushort hh, ll; split2(v, hh, ll);
                    Ch[row * N + c] = hh;
                    Cl[row * N + c] = ll;
                } else {
                    Cf[row * N + c] = v;
                }
            }
        }
    }
}

// ---------------------------------------------------------------------------
// Fused attention: 8 waves x 16 q-rows = 128 q-rows/block, single-buffered.
// K tiles staged via global_load_lds into linear [64][64] with the same
// source-side swizzle; V^T gather + plds unchanged. Swapped QK^T (A=K, B=Q):
// D=[k][q] -> float4 attn stores, 2-shfl row sums. setprio around MFMA.
// ---------------------------------------------------------------------------
__global__ __launch_bounds__(512) void attn_fused(
    const ushort* __restrict__ qh, const ushort* __restrict__ ql,
    float* __restrict__ attn, ushort* __restrict__ oh, ushort* __restrict__ ol)
{
    __shared__ ushort ksh_h[64][64];
    __shared__ ushort ksh_l[64][64];
    __shared__ ushort vth[64][72];       // V^T: [d][k]
    __shared__ ushort plds[8][16][72];   // per-wave p: [q][k]

    const int t    = threadIdx.x;
    const int lane = t & 63;
    const int wv   = t >> 6;
    const int lo   = lane & 15, hi = lane >> 4;
    const int bh   = blockIdx.y;
    const int b    = bh >> 4, h = bh & 15;
    const size_t base = (size_t)b * S_LEN * E3 + h * 192;
    const int q0   = (blockIdx.x << 7) + (wv << 4);

    const int lrow = lane >> 3;
    const int scol = ((lane & 7) ^ lrow) << 3;   // pre-swizzled source col
    const int r0k  = wv << 3;                    // this wave's K chunk (8 rows)
    const int rsw  = (lo & 7) << 3;              // fragment-read swizzle

    bf8 qfh[2], qfl[2];
    #pragma unroll
    for (int st = 0; st < 2; ++st) {
        const size_t off = base + (size_t)(q0 + lo) * E3 + (st << 5) + (hi << 3);
        qfh[st] = *(const bf8*)&qh[off];
        qfl[st] = *(const bf8*)&ql[off];
    }

    // ---- pass 1: denominators
    float ssum = 0.0f;
    for (int kt = 0; kt < S_LEN; kt += 64) {
        __syncthreads();
        {
            const size_t g = base + 64 + (size_t)(kt + r0k + lrow) * E3 + scol;
            gload_lds16(&qh[g], &ksh_h[r0k][0]);
            gload_lds16(&ql[g], &ksh_l[r0k][0]);
        }
        __syncthreads();
        __builtin_amdgcn_s_setprio(1);
        #pragma unroll
        for (int sub = 0; sub < 4; ++sub) {
            f4 acc = {};
            #pragma unroll
            for (int st = 0; st < 2; ++st) {
                const int kc = ((st << 5) + (hi << 3)) ^ rsw;
                bf8 kh = *(const bf8*)&ksh_h[(sub << 4) + lo][kc];
                bf8 kl = *(const bf8*)&ksh_l[(sub << 4) + lo][kc];
                acc = MFMA16(kh, qfh[st], acc);
                acc = MFMA16(kh, qfl[st], acc);
                acc = MFMA16(kl, qfh[st], acc);
            }
            #pragma unroll
            for (int j = 0; j < 4; ++j) ssum += __expf(acc[j]);
        }
        __builtin_amdgcn_s_setprio(0);
    }
    ssum += __shfl_xor(ssum, 16, 64);
    ssum += __shfl_xor(ssum, 32, 64);
    const float inv_s = 1.0f / ssum;

    // ---- pass 2: attention write + PV
    f4 oacc[4] = {};
    for (int kt = 0; kt < S_LEN; kt += 64) {
        __syncthreads();
        {   // stage K via DMA
            const size_t g = base + 64 + (size_t)(kt + r0k + lrow) * E3 + scol;
            gload_lds16(&qh[g], &ksh_h[r0k][0]);
            gload_lds16(&ql[g], &ksh_l[r0k][0]);
        }
        #pragma unroll
        for (int i = 0; i < 2; ++i) {   // stage V^T (transpose gather)
            const int d = t & 63;
            const int k4 = ((t >> 6) + (i << 3)) << 2;
            ushort4 v;
            #pragma unroll
            for (int m = 0; m < 4; ++m)
                ((ushort*)&v)[m] = qh[base + 128 + (size_t)(kt + k4 + m) * E3 + d];
            *(ushort4*)&vth[d][k4] = v;
        }
        __syncthreads();

        #pragma unroll
        for (int sub = 0; sub < 4; ++sub) {
            f4 acc = {};
            __builtin_amdgcn_s_setprio(1);
            #pragma unroll
            for (int st = 0; st < 2; ++st) {
                const int kc = ((st << 5) + (hi << 3)) ^ rsw;
                bf8 kh = *(const bf8*)&ksh_h[(sub << 4) + lo][kc];
                bf8 kl = *(const bf8*)&ksh_l[(sub << 4) + lo][kc];
                acc = MFMA16(kh, qfh[st], acc);
                acc = MFMA16(kh, qfl[st], acc);
                acc = MFMA16(kl, qfh[st], acc);
            }
            __builtin_amdgcn_s_setprio(0);
            float4 pw; ushort4 pb;
            #pragma unroll
            for (int j = 0; j < 4; ++j) {
                float p = __expf(acc[j]) * inv_s;
                ((float*)&pw)[j] = p;
                ((ushort*)&pb)[j] = bf16rn(p);
            }
            *(float4*)&attn[((size_t)bh * S_LEN + q0 + lo) * S_LEN +
                            kt + (sub << 4) + (hi << 2)] = pw;
            *(ushort4*)&plds[wv][lo][(sub << 4) + (hi << 2)] = pb;
        }
        // PV: o += p @ V
        __builtin_amdgcn_s_setprio(1);
        #pragma unroll
        for (int kk = 0; kk < 2; ++kk) {
            bf8 pa = *(const bf8*)&plds[wv][lo][(kk << 5) + (hi << 3)];
            #pragma unroll
            for (int dt = 0; dt < 4; ++dt) {
                bf8 vb = *(const bf8*)&vth[(dt << 4) + lo][(kk << 5) + (hi << 3)];
                oacc[dt] = MFMA16(pa, vb, oacc[dt]);
            }
        }
        __builtin_amdgcn_s_setprio(0);
    }

    // epilogue: split o head planes for out-proj GEMM
    #pragma unroll
    for (int dt = 0; dt < 4; ++dt) {
        #pragma unroll
        for (int j = 0; j < 4; ++j) {
            const size_t row = (size_t)b * S_LEN + q0 + (hi << 2) + j;
            ushort hh, ll; split2(oacc[dt][j], hh, ll);
            oh[row * EDIM + h * 64 + (dt << 4) + lo] = hh;
            ol[row * EDIM + h * 64 + (dt << 4) + lo] = ll;
        }
    }
}

// ---------------------------------------------------------------------------
extern "C" void kernel_launch(void* const* d_in, const int* in_sizes, int n_in,
                              void* d_out, int out_size, void* d_ws, size_t ws_size,
                              hipStream_t stream)
{
    const float* x    = (const float*)d_in[0];
    const float* Wqkv = (const float*)d_in[1];
    const float* bqkv = (const float*)d_in[2];
    const float* Wout = (const float*)d_in[3];
    const float* bout = (const float*)d_in[4];

    float* o_out    = (float*)d_out;
    float* attn_out = o_out + (size_t)NBATCH * S_LEN * DDIM;

    const size_t nQKV = (size_t)NBATCH * S_LEN * E3;
    const size_t nO   = (size_t)NBATCH * S_LEN * EDIM;
    const size_t nWq  = (size_t)DDIM * E3;
    const size_t nWo  = (size_t)EDIM * DDIM;

    ushort* qh    = (ushort*)d_ws;
    ushort* ql    = qh + nQKV;
    ushort* oh    = ql + nQKV;      // doubles as xh before attn
    ushort* ol    = oh + nO;        // doubles as xl before attn
    ushort* wqt_h = ol + nO;
    ushort* wqt_l = wqt_h + nWq;
    ushort* wot_h = wqt_l + nWq;
    ushort* wot_l = wot_h + nWo;

    ushort* xh = oh;
    ushort* xl = ol;

    const int M = NBATCH * S_LEN;  // 4096

    split_plane<<<(int)(nO / 1024), 256, 0, stream>>>(x, xh, xl, (int)nO);
    transpose_split<<<dim3(E3 / 32, DDIM / 32), 256, 0, stream>>>(Wqkv, wqt_h, wqt_l, DDIM, E3);
    transpose_split<<<dim3(DDIM / 32, EDIM / 32), 256, 0, stream>>>(Wout, wot_h, wot_l, EDIM, DDIM);

    gemm_planes<0><<<dim3(E3 / 128, M / 128), 512, 0, stream>>>(
        xh, xl, wqt_h, wqt_l, bqkv, nullptr, qh, ql, M, E3, DDIM);

    attn_fused<<<dim3(S_LEN / 128, NBATCH * NHEAD), 512, 0, stream>>>(
        qh, ql, attn_out, oh, ol);

    gemm_planes<1><<<dim3(DDIM / 128, M / 128), 512, 0, stream>>>(
        oh, ol, wot_h, wot_l, bout, o_out, nullptr, nullptr, M, DDIM, EDIM);
}

// Round 8
// 368.843 us; speedup vs baseline: 1.2304x; 1.1302x over previous
//
#include <hip/hip_runtime.h>
#include <cstdint>

#define S_LEN 2048
#define NBATCH 2
#define NHEAD 16
#define E3 3072
#define EDIM 1024
#define DDIM 1024

typedef __attribute__((ext_vector_type(8))) short bf8;
typedef __attribute__((ext_vector_type(4))) float f4;

#define MFMA16(A, B, C) __builtin_amdgcn_mfma_f32_16x16x32_bf16(A, B, C, 0, 0, 0)

__device__ __forceinline__ ushort bf16rn(float f) {
    unsigned u = __builtin_bit_cast(unsigned, f);
    return (ushort)((u + 0x7fffu + ((u >> 16) & 1u)) >> 16);
}
__device__ __forceinline__ void split2(float f, ushort& h, ushort& l) {
    h = bf16rn(f);
    float hf = __builtin_bit_cast(float, ((unsigned)h) << 16);
    l = bf16rn(f - hf);
}

// global -> LDS direct DMA, 16B per lane (linear dest; source pre-swizzled).
__device__ __forceinline__ void gload_lds16(const ushort* g, ushort* l) {
    __builtin_amdgcn_global_load_lds(
        (const __attribute__((address_space(1))) void*)g,
        (__attribute__((address_space(3))) void*)l, 16, 0, 0);
}

// ---------------------------------------------------------------------------
// Prep 1: split f32 plane -> hi/lo bf16 planes.
// ---------------------------------------------------------------------------
__global__ __launch_bounds__(256) void split_plane(
    const float* __restrict__ X, ushort* __restrict__ Xh, ushort* __restrict__ Xl, int n)
{
    const int i = (blockIdx.x * 256 + threadIdx.x) * 4;
    if (i >= n) return;
    float4 v = *(const float4*)&X[i];
    ushort4 h, l;
    split2(v.x, h.x, l.x); split2(v.y, h.y, l.y);
    split2(v.z, h.z, l.z); split2(v.w, h.w, l.w);
    *(ushort4*)&Xh[i] = h;
    *(ushort4*)&Xl[i] = l;
}

// ---------------------------------------------------------------------------
// Prep 2: W [K][N] f32 -> transposed split planes [N][K] bf16 hi/lo.
// ---------------------------------------------------------------------------
__global__ __launch_bounds__(256) void transpose_split(
    const float* __restrict__ W, ushort* __restrict__ Th, ushort* __restrict__ Tl,
    int K, int N)
{
    __shared__ float tile[32][33];
    const int t  = threadIdx.x;
    const int n0 = blockIdx.x << 5, k0 = blockIdx.y << 5;
    const int c  = t & 31, r = t >> 5;
    #pragma unroll
    for (int i = 0; i < 4; ++i)
        tile[c][r + (i << 3)] = W[(size_t)(k0 + r + (i << 3)) * N + n0 + c];
    __syncthreads();
    #pragma unroll
    for (int i = 0; i < 4; ++i) {
        float v = tile[r + (i << 3)][c];
        ushort hh, ll; split2(v, hh, ll);
        Th[(size_t)(n0 + r + (i << 3)) * K + k0 + c] = hh;
        Tl[(size_t)(n0 + r + (i << 3)) * K + k0 + c] = ll;
    }
}

// ---------------------------------------------------------------------------
// MFMA GEMM, bf16x3, 128x128 tile, BK=64, 512 thr = 8 waves (2x4 of 64x32).
// global_load_lds staging, source-side XOR swizzle (involution, both sides).
// Chunked XCD swizzle on block id (nwg divisible by 8 for both launches).
// MODE 0: C -> split planes (bias; Q cols (c%192<64) scaled 0.125).
// MODE 1: C -> f32 nontemporal (bias).
// ---------------------------------------------------------------------------
template<int MODE>
__global__ __launch_bounds__(512, 4) void gemm_planes(
    const ushort* __restrict__ Ah, const ushort* __restrict__ Al,
    const ushort* __restrict__ Bh, const ushort* __restrict__ Bl,
    const float* __restrict__ bias,
    float* __restrict__ Cf, ushort* __restrict__ Ch, ushort* __restrict__ Cl,
    int M, int N, int K)
{
    __shared__ ushort As_h[128][64];
    __shared__ ushort As_l[128][64];
    __shared__ ushort Bs_h[128][64];
    __shared__ ushort Bs_l[128][64];

    const int t    = threadIdx.x;
    const int lane = t & 63;
    const int w    = t >> 6;
    const int lo   = lane & 15, hi = lane >> 4;
    const int wr   = w >> 2;
    const int wc   = w & 3;

    // XCD-chunked bijective swizzle: XCD orig%8 handles contiguous wgid chunk
    const int nwg  = gridDim.x * gridDim.y;
    const int orig = blockIdx.x + blockIdx.y * gridDim.x;
    const int wgid = (orig & 7) * (nwg >> 3) + (orig >> 3);
    const int rb   = (wgid / gridDim.x) << 7;
    const int cb   = (wgid % gridDim.x) << 7;

    const int lrow = lane >> 3;
    const int scol = ((lane & 7) ^ lrow) << 3;   // pre-swizzled source col
    const int w8   = w << 1;
    const int rsw  = (lo & 7) << 3;              // fragment-read swizzle

    f4 acc[4][2] = {};

    for (int k0 = 0; k0 < K; k0 += 64) {
        __syncthreads();
        #pragma unroll
        for (int i = 0; i < 2; ++i) {
            const int r0  = (w8 + i) << 3;
            const int row = r0 + lrow;
            const size_t ga = (size_t)(rb + row) * K + k0 + scol;
            const size_t gb = (size_t)(cb + row) * K + k0 + scol;
            gload_lds16(&Ah[ga], &As_h[r0][0]);
            gload_lds16(&Al[ga], &As_l[r0][0]);
            gload_lds16(&Bh[gb], &Bs_h[r0][0]);
            gload_lds16(&Bl[gb], &Bs_l[r0][0]);
        }
        __syncthreads();

        __builtin_amdgcn_s_setprio(1);
        #pragma unroll
        for (int st = 0; st < 2; ++st) {
            const int kc = ((st << 5) + (hi << 3)) ^ rsw;
            bf8 a_h[4], a_l[4], b_h[2], b_l[2];
            #pragma unroll
            for (int f = 0; f < 4; ++f) {
                const int r = (wr << 6) + (f << 4) + lo;
                a_h[f] = *(const bf8*)&As_h[r][kc];
                a_l[f] = *(const bf8*)&As_l[r][kc];
            }
            #pragma unroll
            for (int g = 0; g < 2; ++g) {
                const int c = (wc << 5) + (g << 4) + lo;
                b_h[g] = *(const bf8*)&Bs_h[c][kc];
                b_l[g] = *(const bf8*)&Bs_l[c][kc];
            }
            #pragma unroll
            for (int f = 0; f < 4; ++f)
                #pragma unroll
                for (int g = 0; g < 2; ++g) {
                    acc[f][g] = MFMA16(a_h[f], b_h[g], acc[f][g]);
                    acc[f][g] = MFMA16(a_h[f], b_l[g], acc[f][g]);
                    acc[f][g] = MFMA16(a_l[f], b_h[g], acc[f][g]);
                }
        }
        __builtin_amdgcn_s_setprio(0);
    }

    #pragma unroll
    for (int f = 0; f < 4; ++f) {
        #pragma unroll
        for (int g = 0; g < 2; ++g) {
            const int c  = cb + (wc << 5) + (g << 4) + lo;
            const float bv = bias[c];
            const float qs = (MODE == 0 && (c % 192) < 64) ? 0.125f : 1.0f;
            #pragma unroll
            for (int j = 0; j < 4; ++j) {
                const size_t row = (size_t)rb + (wr << 6) + (f << 4) + (hi << 2) + j;
                float v = (acc[f][g][j] + bv) * qs;
                if (MODE == 0) {
                    ushort hh, ll; split2(v, hh, ll);
                    Ch[row * N + c] = hh;
                    Cl[row * N + c] = ll;
                } else {
                    __builtin_nontemporal_store(v, &Cf[row * N + c]);
                }
            }
        }
    }
}

// ---------------------------------------------------------------------------
// Fused attention: 1-D grid, id = qblk*32 + bh  =>  XCD = id%8 = bh%8:
// all 16 q-blocks of one (b,h) share one XCD's L2 (K/V fetched once per XCD).
// 8 waves x 16 q-rows = 128 q-rows/block, single-buffered (3 blocks/CU).
// Swapped QK^T (A=K, B=Q): D=[k][q] -> f4 nontemporal attn stores,
// 2-shfl row sums. setprio around MFMA clusters.
// ---------------------------------------------------------------------------
__global__ __launch_bounds__(512) void attn_fused(
    const ushort* __restrict__ qh, const ushort* __restrict__ ql,
    float* __restrict__ attn, ushort* __restrict__ oh, ushort* __restrict__ ol)
{
    __shared__ ushort ksh_h[64][64];
    __shared__ ushort ksh_l[64][64];
    __shared__ ushort vth[64][72];       // V^T: [d][k]
    __shared__ ushort plds[8][16][72];   // per-wave p: [q][k]

    const int t    = threadIdx.x;
    const int lane = t & 63;
    const int wv   = t >> 6;
    const int lo   = lane & 15, hi = lane >> 4;
    const int bh   = blockIdx.x & 31;          // XCD affinity: bh%8
    const int qblk = blockIdx.x >> 5;
    const int b    = bh >> 4, h = bh & 15;
    const size_t base = (size_t)b * S_LEN * E3 + h * 192;
    const int q0   = (qblk << 7) + (wv << 4);

    const int lrow = lane >> 3;
    const int scol = ((lane & 7) ^ lrow) << 3;
    const int r0k  = wv << 3;
    const int rsw  = (lo & 7) << 3;

    bf8 qfh[2], qfl[2];
    #pragma unroll
    for (int st = 0; st < 2; ++st) {
        const size_t off = base + (size_t)(q0 + lo) * E3 + (st << 5) + (hi << 3);
        qfh[st] = *(const bf8*)&qh[off];
        qfl[st] = *(const bf8*)&ql[off];
    }

    // ---- pass 1: denominators
    float ssum = 0.0f;
    for (int kt = 0; kt < S_LEN; kt += 64) {
        __syncthreads();
        {
            const size_t g = base + 64 + (size_t)(kt + r0k + lrow) * E3 + scol;
            gload_lds16(&qh[g], &ksh_h[r0k][0]);
            gload_lds16(&ql[g], &ksh_l[r0k][0]);
        }
        __syncthreads();
        __builtin_amdgcn_s_setprio(1);
        #pragma unroll
        for (int sub = 0; sub < 4; ++sub) {
            f4 acc = {};
            #pragma unroll
            for (int st = 0; st < 2; ++st) {
                const int kc = ((st << 5) + (hi << 3)) ^ rsw;
                bf8 kh = *(const bf8*)&ksh_h[(sub << 4) + lo][kc];
                bf8 kl = *(const bf8*)&ksh_l[(sub << 4) + lo][kc];
                acc = MFMA16(kh, qfh[st], acc);
                acc = MFMA16(kh, qfl[st], acc);
                acc = MFMA16(kl, qfh[st], acc);
            }
            #pragma unroll
            for (int j = 0; j < 4; ++j) ssum += __expf(acc[j]);
        }
        __builtin_amdgcn_s_setprio(0);
    }
    ssum += __shfl_xor(ssum, 16, 64);
    ssum += __shfl_xor(ssum, 32, 64);
    const float inv_s = 1.0f / ssum;

    // ---- pass 2: attention write + PV
    f4 oacc[4] = {};
    for (int kt = 0; kt < S_LEN; kt += 64) {
        __syncthreads();
        {
            const size_t g = base + 64 + (size_t)(kt + r0k + lrow) * E3 + scol;
            gload_lds16(&qh[g], &ksh_h[r0k][0]);
            gload_lds16(&ql[g], &ksh_l[r0k][0]);
        }
        #pragma unroll
        for (int i = 0; i < 2; ++i) {   // stage V^T (row-coalesced 128B reads)
            const int d = t & 63;
            const int k4 = ((t >> 6) + (i << 3)) << 2;
            ushort4 v;
            #pragma unroll
            for (int m = 0; m < 4; ++m)
                ((ushort*)&v)[m] = qh[base + 128 + (size_t)(kt + k4 + m) * E3 + d];
            *(ushort4*)&vth[d][k4] = v;
        }
        __syncthreads();

        #pragma unroll
        for (int sub = 0; sub < 4; ++sub) {
            f4 acc = {};
            __builtin_amdgcn_s_setprio(1);
            #pragma unroll
            for (int st = 0; st < 2; ++st) {
                const int kc = ((st << 5) + (hi << 3)) ^ rsw;
                bf8 kh = *(const bf8*)&ksh_h[(sub << 4) + lo][kc];
                bf8 kl = *(const bf8*)&ksh_l[(sub << 4) + lo][kc];
                acc = MFMA16(kh, qfh[st], acc);
                acc = MFMA16(kh, qfl[st], acc);
                acc = MFMA16(kl, qfh[st], acc);
            }
            __builtin_amdgcn_s_setprio(0);
            f4 pw; ushort4 pb;
            #pragma unroll
            for (int j = 0; j < 4; ++j) {
                float p = __expf(acc[j]) * inv_s;
                pw[j] = p;
                ((ushort*)&pb)[j] = bf16rn(p);
            }
            __builtin_nontemporal_store(pw,
                (f4*)&attn[((size_t)bh * S_LEN + q0 + lo) * S_LEN +
                           kt + (sub << 4) + (hi << 2)]);
            *(ushort4*)&plds[wv][lo][(sub << 4) + (hi << 2)] = pb;
        }
        // PV: o += p @ V
        __builtin_amdgcn_s_setprio(1);
        #pragma unroll
        for (int kk = 0; kk < 2; ++kk) {
            bf8 pa = *(const bf8*)&plds[wv][lo][(kk << 5) + (hi << 3)];
            #pragma unroll
            for (int dt = 0; dt < 4; ++dt) {
                bf8 vb = *(const bf8*)&vth[(dt << 4) + lo][(kk << 5) + (hi << 3)];
                oacc[dt] = MFMA16(pa, vb, oacc[dt]);
            }
        }
        __builtin_amdgcn_s_setprio(0);
    }

    // epilogue: split o head planes for out-proj GEMM (re-read: cached stores)
    #pragma unroll
    for (int dt = 0; dt < 4; ++dt) {
        #pragma unroll
        for (int j = 0; j < 4; ++j) {
            const size_t row = (size_t)b * S_LEN + q0 + (hi << 2) + j;
            ushort hh, ll; split2(oacc[dt][j], hh, ll);
            oh[row * EDIM + h * 64 + (dt << 4) + lo] = hh;
            ol[row * EDIM + h * 64 + (dt << 4) + lo] = ll;
        }
    }
}

// ---------------------------------------------------------------------------
extern "C" void kernel_launch(void* const* d_in, const int* in_sizes, int n_in,
                              void* d_out, int out_size, void* d_ws, size_t ws_size,
                              hipStream_t stream)
{
    const float* x    = (const float*)d_in[0];
    const float* Wqkv = (const float*)d_in[1];
    const float* bqkv = (const float*)d_in[2];
    const float* Wout = (const float*)d_in[3];
    const float* bout = (const float*)d_in[4];

    float* o_out    = (float*)d_out;
    float* attn_out = o_out + (size_t)NBATCH * S_LEN * DDIM;

    const size_t nQKV = (size_t)NBATCH * S_LEN * E3;
    const size_t nO   = (size_t)NBATCH * S_LEN * EDIM;
    const size_t nWq  = (size_t)DDIM * E3;
    const size_t nWo  = (size_t)EDIM * DDIM;

    ushort* qh    = (ushort*)d_ws;
    ushort* ql    = qh + nQKV;
    ushort* oh    = ql + nQKV;      // doubles as xh before attn
    ushort* ol    = oh + nO;        // doubles as xl before attn
    ushort* wqt_h = ol + nO;
    ushort* wqt_l = wqt_h + nWq;
    ushort* wot_h = wqt_l + nWq;
    ushort* wot_l = wot_h + nWo;

    ushort* xh = oh;
    ushort* xl = ol;

    const int M = NBATCH * S_LEN;  // 4096

    split_plane<<<(int)(nO / 1024), 256, 0, stream>>>(x, xh, xl, (int)nO);
    transpose_split<<<dim3(E3 / 32, DDIM / 32), 256, 0, stream>>>(Wqkv, wqt_h, wqt_l, DDIM, E3);
    transpose_split<<<dim3(DDIM / 32, EDIM / 32), 256, 0, stream>>>(Wout, wot_h, wot_l, EDIM, DDIM);

    gemm_planes<0><<<dim3(E3 / 128, M / 128), 512, 0, stream>>>(
        xh, xl, wqt_h, wqt_l, bqkv, nullptr, qh, ql, M, E3, DDIM);

    attn_fused<<<(S_LEN / 128) * NBATCH * NHEAD, 512, 0, stream>>>(
        qh, ql, attn_out, oh, ol);

    gemm_planes<1><<<dim3(DDIM / 128, M / 128), 512, 0, stream>>>(
        oh, ol, wot_h, wot_l, bout, o_out, nullptr, nullptr, M, DDIM, EDIM);
}

// Round 9
// 330.991 us; speedup vs baseline: 1.3711x; 1.1144x over previous
//
#include <hip/hip_runtime.h>
#include <cstdint>

#define S_LEN 2048
#define NBATCH 2
#define NHEAD 16
#define E3 3072
#define EDIM 1024
#define DDIM 1024

typedef __attribute__((ext_vector_type(8))) short bf8;
typedef __attribute__((ext_vector_type(4))) float f4;

#define MFMA16(A, B, C) __builtin_amdgcn_mfma_f32_16x16x32_bf16(A, B, C, 0, 0, 0)

__device__ __forceinline__ ushort bf16rn(float f) {
    unsigned u = __builtin_bit_cast(unsigned, f);
    return (ushort)((u + 0x7fffu + ((u >> 16) & 1u)) >> 16);
}
__device__ __forceinline__ void split2(float f, ushort& h, ushort& l) {
    h = bf16rn(f);
    float hf = __builtin_bit_cast(float, ((unsigned)h) << 16);
    l = bf16rn(f - hf);
}

// global -> LDS direct DMA, 16B per lane (linear dest; source pre-swizzled).
__device__ __forceinline__ void gload_lds16(const ushort* g, ushort* l) {
    __builtin_amdgcn_global_load_lds(
        (const __attribute__((address_space(1))) void*)g,
        (__attribute__((address_space(3))) void*)l, 16, 0, 0);
}

// ---------------------------------------------------------------------------
// Prep 1: split f32 plane -> hi/lo bf16 planes.
// ---------------------------------------------------------------------------
__global__ __launch_bounds__(256) void split_plane(
    const float* __restrict__ X, ushort* __restrict__ Xh, ushort* __restrict__ Xl, int n)
{
    const int i = (blockIdx.x * 256 + threadIdx.x) * 4;
    if (i >= n) return;
    float4 v = *(const float4*)&X[i];
    ushort4 h, l;
    split2(v.x, h.x, l.x); split2(v.y, h.y, l.y);
    split2(v.z, h.z, l.z); split2(v.w, h.w, l.w);
    *(ushort4*)&Xh[i] = h;
    *(ushort4*)&Xl[i] = l;
}

// ---------------------------------------------------------------------------
// Prep 2: W [K][N] f32 -> transposed split planes [N][K] bf16 hi(/lo).
// ---------------------------------------------------------------------------
__global__ __launch_bounds__(256) void transpose_split(
    const float* __restrict__ W, ushort* __restrict__ Th, ushort* __restrict__ Tl,
    int K, int N)
{
    __shared__ float tile[32][33];
    const int t  = threadIdx.x;
    const int n0 = blockIdx.x << 5, k0 = blockIdx.y << 5;
    const int c  = t & 31, r = t >> 5;
    #pragma unroll
    for (int i = 0; i < 4; ++i)
        tile[c][r + (i << 3)] = W[(size_t)(k0 + r + (i << 3)) * N + n0 + c];
    __syncthreads();
    #pragma unroll
    for (int i = 0; i < 4; ++i) {
        float v = tile[r + (i << 3)][c];
        ushort hh, ll; split2(v, hh, ll);
        Th[(size_t)(n0 + r + (i << 3)) * K + k0 + c] = hh;
        if (Tl) Tl[(size_t)(n0 + r + (i << 3)) * K + k0 + c] = ll;
    }
}

// ---------------------------------------------------------------------------
// MFMA GEMM, 128x128 tile, BK=64, 512 thr = 8 waves (2x4 of 64x32).
// global_load_lds staging, source-side XOR swizzle (involution, both sides).
// MODE 0 (qkv): bf16x2 = A_h*B_h + A_l*B_h (W hi plane only; 3-plane LDS);
//               C -> hi plane only (bias; Q cols (c%192<64) scaled 0.125).
// MODE 1 (out): bf16x3; C -> f32 nontemporal (bias).
// ---------------------------------------------------------------------------
template<int MODE>
__global__ __launch_bounds__(512, 4) void gemm_planes(
    const ushort* __restrict__ Ah, const ushort* __restrict__ Al,
    const ushort* __restrict__ Bh, const ushort* __restrict__ Bl,
    const float* __restrict__ bias,
    float* __restrict__ Cf, ushort* __restrict__ Ch,
    int M, int N, int K)
{
    constexpr int NP = (MODE == 0) ? 3 : 4;
    __shared__ ushort smem[NP * 128 * 64];
    ushort (*As_h)[64] = (ushort(*)[64])(smem);
    ushort (*As_l)[64] = (ushort(*)[64])(smem + 128 * 64);
    ushort (*Bs_h)[64] = (ushort(*)[64])(smem + 2 * 128 * 64);
    ushort (*Bs_l)[64] = (ushort(*)[64])(smem + 3 * 128 * 64);  // MODE 1 only

    const int t    = threadIdx.x;
    const int lane = t & 63;
    const int w    = t >> 6;
    const int lo   = lane & 15, hi = lane >> 4;
    const int wr   = w >> 2;
    const int wc   = w & 3;

    // XCD-chunked bijective swizzle
    const int nwg  = gridDim.x * gridDim.y;
    const int orig = blockIdx.x + blockIdx.y * gridDim.x;
    const int wgid = (orig & 7) * (nwg >> 3) + (orig >> 3);
    const int rb   = (wgid / gridDim.x) << 7;
    const int cb   = (wgid % gridDim.x) << 7;

    const int lrow = lane >> 3;
    const int scol = ((lane & 7) ^ lrow) << 3;   // pre-swizzled source col
    const int w8   = w << 1;
    const int rsw  = (lo & 7) << 3;              // fragment-read swizzle

    f4 acc[4][2] = {};

    for (int k0 = 0; k0 < K; k0 += 64) {
        __syncthreads();
        #pragma unroll
        for (int i = 0; i < 2; ++i) {
            const int r0  = (w8 + i) << 3;
            const int row = r0 + lrow;
            const size_t ga = (size_t)(rb + row) * K + k0 + scol;
            const size_t gb = (size_t)(cb + row) * K + k0 + scol;
            gload_lds16(&Ah[ga], &As_h[r0][0]);
            gload_lds16(&Al[ga], &As_l[r0][0]);
            gload_lds16(&Bh[gb], &Bs_h[r0][0]);
            if constexpr (MODE == 1) gload_lds16(&Bl[gb], &Bs_l[r0][0]);
        }
        __syncthreads();

        __builtin_amdgcn_s_setprio(1);
        #pragma unroll
        for (int st = 0; st < 2; ++st) {
            const int kc = ((st << 5) + (hi << 3)) ^ rsw;
            bf8 a_h[4], a_l[4], b_h[2], b_l[2];
            #pragma unroll
            for (int f = 0; f < 4; ++f) {
                const int r = (wr << 6) + (f << 4) + lo;
                a_h[f] = *(const bf8*)&As_h[r][kc];
                a_l[f] = *(const bf8*)&As_l[r][kc];
            }
            #pragma unroll
            for (int g = 0; g < 2; ++g) {
                const int c = (wc << 5) + (g << 4) + lo;
                b_h[g] = *(const bf8*)&Bs_h[c][kc];
                if constexpr (MODE == 1) b_l[g] = *(const bf8*)&Bs_l[c][kc];
            }
            #pragma unroll
            for (int f = 0; f < 4; ++f)
                #pragma unroll
                for (int g = 0; g < 2; ++g) {
                    acc[f][g] = MFMA16(a_h[f], b_h[g], acc[f][g]);
                    acc[f][g] = MFMA16(a_l[f], b_h[g], acc[f][g]);
                    if constexpr (MODE == 1)
                        acc[f][g] = MFMA16(a_h[f], b_l[g], acc[f][g]);
                }
        }
        __builtin_amdgcn_s_setprio(0);
    }

    #pragma unroll
    for (int f = 0; f < 4; ++f) {
        #pragma unroll
        for (int g = 0; g < 2; ++g) {
            const int c  = cb + (wc << 5) + (g << 4) + lo;
            const float bv = bias[c];
            const float qs = (MODE == 0 && (c % 192) < 64) ? 0.125f : 1.0f;
            #pragma unroll
            for (int j = 0; j < 4; ++j) {
                const size_t row = (size_t)rb + (wr << 6) + (f << 4) + (hi << 2) + j;
                float v = (acc[f][g][j] + bv) * qs;
                if constexpr (MODE == 0) {
                    Ch[row * N + c] = bf16rn(v);
                } else {
                    __builtin_nontemporal_store(v, &Cf[row * N + c]);
                }
            }
        }
    }
}

// ---------------------------------------------------------------------------
// Fused attention, single-bf16 QK^T (hi planes only; identical operands in
// both passes => denominator exactly consistent with written numerators).
// 1-D grid, id = qblk*32 + bh => XCD = bh%8 (K/V L2 affinity).
// 8 waves x 16 q-rows = 128 q-rows/block. LDS 35 KB -> 4 blocks/CU.
// Swapped QK^T (A=K, B=Q): D=[k][q] -> f4 nontemporal attn stores,
// 2-shfl row sums. setprio around MFMA clusters.
// ---------------------------------------------------------------------------
__global__ __launch_bounds__(512) void attn_fused(
    const ushort* __restrict__ qh,
    float* __restrict__ attn, ushort* __restrict__ oh, ushort* __restrict__ ol)
{
    __shared__ ushort ksh_h[64][64];
    __shared__ ushort vth[64][72];       // V^T: [d][k]
    __shared__ ushort plds[8][16][72];   // per-wave p: [q][k]

    const int t    = threadIdx.x;
    const int lane = t & 63;
    const int wv   = t >> 6;
    const int lo   = lane & 15, hi = lane >> 4;
    const int bh   = blockIdx.x & 31;          // XCD affinity: bh%8
    const int qblk = blockIdx.x >> 5;
    const int b    = bh >> 4, h = bh & 15;
    const size_t base = (size_t)b * S_LEN * E3 + h * 192;
    const int q0   = (qblk << 7) + (wv << 4);

    const int lrow = lane >> 3;
    const int scol = ((lane & 7) ^ lrow) << 3;
    const int r0k  = wv << 3;
    const int rsw  = (lo & 7) << 3;

    bf8 qfh[2];
    #pragma unroll
    for (int st = 0; st < 2; ++st) {
        const size_t off = base + (size_t)(q0 + lo) * E3 + (st << 5) + (hi << 3);
        qfh[st] = *(const bf8*)&qh[off];
    }

    // ---- pass 1: denominators
    float ssum = 0.0f;
    for (int kt = 0; kt < S_LEN; kt += 64) {
        __syncthreads();
        {
            const size_t g = base + 64 + (size_t)(kt + r0k + lrow) * E3 + scol;
            gload_lds16(&qh[g], &ksh_h[r0k][0]);
        }
        __syncthreads();
        __builtin_amdgcn_s_setprio(1);
        #pragma unroll
        for (int sub = 0; sub < 4; ++sub) {
            f4 acc = {};
            #pragma unroll
            for (int st = 0; st < 2; ++st) {
                const int kc = ((st << 5) + (hi << 3)) ^ rsw;
                bf8 kh = *(const bf8*)&ksh_h[(sub << 4) + lo][kc];
                acc = MFMA16(kh, qfh[st], acc);
            }
            #pragma unroll
            for (int j = 0; j < 4; ++j) ssum += __expf(acc[j]);
        }
        __builtin_amdgcn_s_setprio(0);
    }
    ssum += __shfl_xor(ssum, 16, 64);
    ssum += __shfl_xor(ssum, 32, 64);
    const float inv_s = 1.0f / ssum;

    // ---- pass 2: attention write + PV
    f4 oacc[4] = {};
    for (int kt = 0; kt < S_LEN; kt += 64) {
        __syncthreads();
        {
            const size_t g = base + 64 + (size_t)(kt + r0k + lrow) * E3 + scol;
            gload_lds16(&qh[g], &ksh_h[r0k][0]);
        }
        #pragma unroll
        for (int i = 0; i < 2; ++i) {   // stage V^T (row-coalesced reads)
            const int d = t & 63;
            const int k4 = ((t >> 6) + (i << 3)) << 2;
            ushort4 v;
            #pragma unroll
            for (int m = 0; m < 4; ++m)
                ((ushort*)&v)[m] = qh[base + 128 + (size_t)(kt + k4 + m) * E3 + d];
            *(ushort4*)&vth[d][k4] = v;
        }
        __syncthreads();

        #pragma unroll
        for (int sub = 0; sub < 4; ++sub) {
            f4 acc = {};
            __builtin_amdgcn_s_setprio(1);
            #pragma unroll
            for (int st = 0; st < 2; ++st) {
                const int kc = ((st << 5) + (hi << 3)) ^ rsw;
                bf8 kh = *(const bf8*)&ksh_h[(sub << 4) + lo][kc];
                acc = MFMA16(kh, qfh[st], acc);
            }
            __builtin_amdgcn_s_setprio(0);
            f4 pw; ushort4 pb;
            #pragma unroll
            for (int j = 0; j < 4; ++j) {
                float p = __expf(acc[j]) * inv_s;
                pw[j] = p;
                ((ushort*)&pb)[j] = bf16rn(p);
            }
            __builtin_nontemporal_store(pw,
                (f4*)&attn[((size_t)bh * S_LEN + q0 + lo) * S_LEN +
                           kt + (sub << 4) + (hi << 2)]);
            *(ushort4*)&plds[wv][lo][(sub << 4) + (hi << 2)] = pb;
        }
        // PV: o += p @ V
        __builtin_amdgcn_s_setprio(1);
        #pragma unroll
        for (int kk = 0; kk < 2; ++kk) {
            bf8 pa = *(const bf8*)&plds[wv][lo][(kk << 5) + (hi << 3)];
            #pragma unroll
            for (int dt = 0; dt < 4; ++dt) {
                bf8 vb = *(const bf8*)&vth[(dt << 4) + lo][(kk << 5) + (hi << 3)];
                oacc[dt] = MFMA16(pa, vb, oacc[dt]);
            }
        }
        __builtin_amdgcn_s_setprio(0);
    }

    // epilogue: split o head planes for out-proj GEMM
    #pragma unroll
    for (int dt = 0; dt < 4; ++dt) {
        #pragma unroll
        for (int j = 0; j < 4; ++j) {
            const size_t row = (size_t)b * S_LEN + q0 + (hi << 2) + j;
            ushort hh, ll; split2(oacc[dt][j], hh, ll);
            oh[row * EDIM + h * 64 + (dt << 4) + lo] = hh;
            ol[row * EDIM + h * 64 + (dt << 4) + lo] = ll;
        }
    }
}

// ---------------------------------------------------------------------------
extern "C" void kernel_launch(void* const* d_in, const int* in_sizes, int n_in,
                              void* d_out, int out_size, void* d_ws, size_t ws_size,
                              hipStream_t stream)
{
    const float* x    = (const float*)d_in[0];
    const float* Wqkv = (const float*)d_in[1];
    const float* bqkv = (const float*)d_in[2];
    const float* Wout = (const float*)d_in[3];
    const float* bout = (const float*)d_in[4];

    float* o_out    = (float*)d_out;
    float* attn_out = o_out + (size_t)NBATCH * S_LEN * DDIM;

    const size_t nQKV = (size_t)NBATCH * S_LEN * E3;
    const size_t nO   = (size_t)NBATCH * S_LEN * EDIM;
    const size_t nWq  = (size_t)DDIM * E3;
    const size_t nWo  = (size_t)EDIM * DDIM;

    ushort* qh    = (ushort*)d_ws;                // qkv hi plane
    ushort* oh    = qh + nQKV;                    // o-head hi (xh before attn)
    ushort* ol    = oh + nO;                      // o-head lo (xl before attn)
    ushort* wqt_h = ol + nO;
    ushort* wot_h = wqt_h + nWq;
    ushort* wot_l = wot_h + nWo;

    ushort* xh = oh;   // overlay: x planes dead after gemm1
    ushort* xl = ol;

    const int M = NBATCH * S_LEN;  // 4096

    split_plane<<<(int)(nO / 1024), 256, 0, stream>>>(x, xh, xl, (int)nO);
    transpose_split<<<dim3(E3 / 32, DDIM / 32), 256, 0, stream>>>(
        Wqkv, wqt_h, nullptr, DDIM, E3);
    transpose_split<<<dim3(DDIM / 32, EDIM / 32), 256, 0, stream>>>(
        Wout, wot_h, wot_l, EDIM, DDIM);

    // K1: qkv = x @ Wqkv + bqkv (bf16x2, hi-plane output, Q pre-scaled)
    gemm_planes<0><<<dim3(E3 / 128, M / 128), 512, 0, stream>>>(
        xh, xl, wqt_h, nullptr, bqkv, nullptr, qh, M, E3, DDIM);

    // K2: fused attention (single-bf16 QK^T both passes)
    attn_fused<<<(S_LEN / 128) * NBATCH * NHEAD, 512, 0, stream>>>(
        qh, attn_out, oh, ol);

    // K3: o = o_head @ Wout + bout (bf16x3)
    gemm_planes<1><<<dim3(DDIM / 128, M / 128), 512, 0, stream>>>(
        oh, ol, wot_h, wot_l, bout, o_out, nullptr, M, DDIM, EDIM);
}

// Round 10
// 300.505 us; speedup vs baseline: 1.5101x; 1.1014x over previous
//
#include <hip/hip_runtime.h>
#include <cstdint>

#define S_LEN 2048
#define NBATCH 2
#define NHEAD 16
#define E3 3072
#define EDIM 1024
#define DDIM 1024

typedef __attribute__((ext_vector_type(8))) short bf8;
typedef __attribute__((ext_vector_type(4))) float f4;

#define MFMA16(A, B, C) __builtin_amdgcn_mfma_f32_16x16x32_bf16(A, B, C, 0, 0, 0)

__device__ __forceinline__ ushort bf16rn(float f) {
    unsigned u = __builtin_bit_cast(unsigned, f);
    return (ushort)((u + 0x7fffu + ((u >> 16) & 1u)) >> 16);
}
__device__ __forceinline__ void split2(float f, ushort& h, ushort& l) {
    h = bf16rn(f);
    float hf = __builtin_bit_cast(float, ((unsigned)h) << 16);
    l = bf16rn(f - hf);
}

// global -> LDS direct DMA, 16B per lane (linear dest; source pre-swizzled).
__device__ __forceinline__ void gload_lds16(const ushort* g, ushort* l) {
    __builtin_amdgcn_global_load_lds(
        (const __attribute__((address_space(1))) void*)g,
        (__attribute__((address_space(3))) void*)l, 16, 0, 0);
}

// ---------------------------------------------------------------------------
// Prep 1: cast f32 -> bf16 plane (RN).
// ---------------------------------------------------------------------------
__global__ __launch_bounds__(256) void cast_plane(
    const float* __restrict__ X, ushort* __restrict__ Xh, int n)
{
    const int i = (blockIdx.x * 256 + threadIdx.x) * 4;
    if (i >= n) return;
    float4 v = *(const float4*)&X[i];
    ushort4 h;
    h.x = bf16rn(v.x); h.y = bf16rn(v.y); h.z = bf16rn(v.z); h.w = bf16rn(v.w);
    *(ushort4*)&Xh[i] = h;
}

// ---------------------------------------------------------------------------
// Prep 2: W [K][N] f32 -> transposed bf16 plane [N][K].
// ---------------------------------------------------------------------------
__global__ __launch_bounds__(256) void transpose_cast(
    const float* __restrict__ W, ushort* __restrict__ Th, int K, int N)
{
    __shared__ float tile[32][33];
    const int t  = threadIdx.x;
    const int n0 = blockIdx.x << 5, k0 = blockIdx.y << 5;
    const int c  = t & 31, r = t >> 5;
    #pragma unroll
    for (int i = 0; i < 4; ++i)
        tile[c][r + (i << 3)] = W[(size_t)(k0 + r + (i << 3)) * N + n0 + c];
    __syncthreads();
    #pragma unroll
    for (int i = 0; i < 4; ++i)
        Th[(size_t)(n0 + r + (i << 3)) * K + k0 + c] = bf16rn(tile[r + (i << 3)][c]);
}

// ---------------------------------------------------------------------------
// Plain bf16 MFMA GEMM, 128x128 tile, BK=64, 512 thr = 8 waves (2x4 of 64x32).
// A [M][K] bf16, B [N][K] bf16 (pre-transposed). global_load_lds staging with
// source-side XOR swizzle (involution, applied on reads too). XCD-chunked
// block swizzle. MODE 0: C -> bf16 (bias; Q cols (c%192<64) scaled 0.125).
// MODE 1: C -> f32 nontemporal (bias).
// ---------------------------------------------------------------------------
template<int MODE>
__global__ __launch_bounds__(512, 4) void gemm_bf16(
    const ushort* __restrict__ Ah, const ushort* __restrict__ Bh,
    const float* __restrict__ bias,
    float* __restrict__ Cf, ushort* __restrict__ Ch,
    int M, int N, int K)
{
    __shared__ ushort As[128][64];
    __shared__ ushort Bs[128][64];

    const int t    = threadIdx.x;
    const int lane = t & 63;
    const int w    = t >> 6;
    const int lo   = lane & 15, hi = lane >> 4;
    const int wr   = w >> 2;
    const int wc   = w & 3;

    // XCD-chunked bijective swizzle
    const int nwg  = gridDim.x * gridDim.y;
    const int orig = blockIdx.x + blockIdx.y * gridDim.x;
    const int wgid = (orig & 7) * (nwg >> 3) + (orig >> 3);
    const int rb   = (wgid / gridDim.x) << 7;
    const int cb   = (wgid % gridDim.x) << 7;

    const int lrow = lane >> 3;
    const int scol = ((lane & 7) ^ lrow) << 3;   // pre-swizzled source col
    const int w8   = w << 1;
    const int rsw  = (lo & 7) << 3;              // fragment-read swizzle

    f4 acc[4][2] = {};

    for (int k0 = 0; k0 < K; k0 += 64) {
        __syncthreads();
        #pragma unroll
        for (int i = 0; i < 2; ++i) {
            const int r0  = (w8 + i) << 3;
            const int row = r0 + lrow;
            gload_lds16(&Ah[(size_t)(rb + row) * K + k0 + scol], &As[r0][0]);
            gload_lds16(&Bh[(size_t)(cb + row) * K + k0 + scol], &Bs[r0][0]);
        }
        __syncthreads();

        __builtin_amdgcn_s_setprio(1);
        #pragma unroll
        for (int st = 0; st < 2; ++st) {
            const int kc = ((st << 5) + (hi << 3)) ^ rsw;
            bf8 a[4], bfr[2];
            #pragma unroll
            for (int f = 0; f < 4; ++f)
                a[f] = *(const bf8*)&As[(wr << 6) + (f << 4) + lo][kc];
            #pragma unroll
            for (int g = 0; g < 2; ++g)
                bfr[g] = *(const bf8*)&Bs[(wc << 5) + (g << 4) + lo][kc];
            #pragma unroll
            for (int f = 0; f < 4; ++f)
                #pragma unroll
                for (int g = 0; g < 2; ++g)
                    acc[f][g] = MFMA16(a[f], bfr[g], acc[f][g]);
        }
        __builtin_amdgcn_s_setprio(0);
    }

    #pragma unroll
    for (int f = 0; f < 4; ++f) {
        #pragma unroll
        for (int g = 0; g < 2; ++g) {
            const int c  = cb + (wc << 5) + (g << 4) + lo;
            const float bv = bias[c];
            const float qs = (MODE == 0 && (c % 192) < 64) ? 0.125f : 1.0f;
            #pragma unroll
            for (int j = 0; j < 4; ++j) {
                const size_t row = (size_t)rb + (wr << 6) + (f << 4) + (hi << 2) + j;
                float v = (acc[f][g][j] + bv) * qs;
                if constexpr (MODE == 0) {
                    Ch[row * N + c] = bf16rn(v);
                } else {
                    __builtin_nontemporal_store(v, &Cf[row * N + c]);
                }
            }
        }
    }
}

// ---------------------------------------------------------------------------
// Fused attention, single-bf16 QK^T (identical operands in both passes =>
// denominator exactly consistent with written numerators).
// 1-D grid, id = qblk*32 + bh => XCD = bh%8 (K/V L2 affinity).
// 8 waves x 16 q-rows = 128 q-rows/block. Swapped QK^T (A=K, B=Q):
// D=[k][q] -> f4 nontemporal attn stores, 2-shfl row sums.
// ---------------------------------------------------------------------------
__global__ __launch_bounds__(512) void attn_fused(
    const ushort* __restrict__ qh,
    float* __restrict__ attn, ushort* __restrict__ oh)
{
    __shared__ ushort ksh_h[64][64];
    __shared__ ushort vth[64][72];       // V^T: [d][k]
    __shared__ ushort plds[8][16][72];   // per-wave p: [q][k]

    const int t    = threadIdx.x;
    const int lane = t & 63;
    const int wv   = t >> 6;
    const int lo   = lane & 15, hi = lane >> 4;
    const int bh   = blockIdx.x & 31;          // XCD affinity: bh%8
    const int qblk = blockIdx.x >> 5;
    const int b    = bh >> 4, h = bh & 15;
    const size_t base = (size_t)b * S_LEN * E3 + h * 192;
    const int q0   = (qblk << 7) + (wv << 4);

    const int lrow = lane >> 3;
    const int scol = ((lane & 7) ^ lrow) << 3;
    const int r0k  = wv << 3;
    const int rsw  = (lo & 7) << 3;

    bf8 qfh[2];
    #pragma unroll
    for (int st = 0; st < 2; ++st) {
        const size_t off = base + (size_t)(q0 + lo) * E3 + (st << 5) + (hi << 3);
        qfh[st] = *(const bf8*)&qh[off];
    }

    // ---- pass 1: denominators
    float ssum = 0.0f;
    for (int kt = 0; kt < S_LEN; kt += 64) {
        __syncthreads();
        {
            const size_t g = base + 64 + (size_t)(kt + r0k + lrow) * E3 + scol;
            gload_lds16(&qh[g], &ksh_h[r0k][0]);
        }
        __syncthreads();
        __builtin_amdgcn_s_setprio(1);
        #pragma unroll
        for (int sub = 0; sub < 4; ++sub) {
            f4 acc = {};
            #pragma unroll
            for (int st = 0; st < 2; ++st) {
                const int kc = ((st << 5) + (hi << 3)) ^ rsw;
                bf8 kh = *(const bf8*)&ksh_h[(sub << 4) + lo][kc];
                acc = MFMA16(kh, qfh[st], acc);
            }
            #pragma unroll
            for (int j = 0; j < 4; ++j) ssum += __expf(acc[j]);
        }
        __builtin_amdgcn_s_setprio(0);
    }
    ssum += __shfl_xor(ssum, 16, 64);
    ssum += __shfl_xor(ssum, 32, 64);
    const float inv_s = 1.0f / ssum;

    // ---- pass 2: attention write + PV
    f4 oacc[4] = {};
    for (int kt = 0; kt < S_LEN; kt += 64) {
        __syncthreads();
        {
            const size_t g = base + 64 + (size_t)(kt + r0k + lrow) * E3 + scol;
            gload_lds16(&qh[g], &ksh_h[r0k][0]);
        }
        #pragma unroll
        for (int i = 0; i < 2; ++i) {   // stage V^T (row-coalesced reads)
            const int d = t & 63;
            const int k4 = ((t >> 6) + (i << 3)) << 2;
            ushort4 v;
            #pragma unroll
            for (int m = 0; m < 4; ++m)
                ((ushort*)&v)[m] = qh[base + 128 + (size_t)(kt + k4 + m) * E3 + d];
            *(ushort4*)&vth[d][k4] = v;
        }
        __syncthreads();

        #pragma unroll
        for (int sub = 0; sub < 4; ++sub) {
            f4 acc = {};
            __builtin_amdgcn_s_setprio(1);
            #pragma unroll
            for (int st = 0; st < 2; ++st) {
                const int kc = ((st << 5) + (hi << 3)) ^ rsw;
                bf8 kh = *(const bf8*)&ksh_h[(sub << 4) + lo][kc];
                acc = MFMA16(kh, qfh[st], acc);
            }
            __builtin_amdgcn_s_setprio(0);
            f4 pw; ushort4 pb;
            #pragma unroll
            for (int j = 0; j < 4; ++j) {
                float p = __expf(acc[j]) * inv_s;
                pw[j] = p;
                ((ushort*)&pb)[j] = bf16rn(p);
            }
            __builtin_nontemporal_store(pw,
                (f4*)&attn[((size_t)bh * S_LEN + q0 + lo) * S_LEN +
                           kt + (sub << 4) + (hi << 2)]);
            *(ushort4*)&plds[wv][lo][(sub << 4) + (hi << 2)] = pb;
        }
        // PV: o += p @ V
        __builtin_amdgcn_s_setprio(1);
        #pragma unroll
        for (int kk = 0; kk < 2; ++kk) {
            bf8 pa = *(const bf8*)&plds[wv][lo][(kk << 5) + (hi << 3)];
            #pragma unroll
            for (int dt = 0; dt < 4; ++dt) {
                bf8 vb = *(const bf8*)&vth[(dt << 4) + lo][(kk << 5) + (hi << 3)];
                oacc[dt] = MFMA16(pa, vb, oacc[dt]);
            }
        }
        __builtin_amdgcn_s_setprio(0);
    }

    // epilogue: o head -> bf16 (single plane; gemm2 is plain bf16)
    #pragma unroll
    for (int dt = 0; dt < 4; ++dt) {
        #pragma unroll
        for (int j = 0; j < 4; ++j) {
            const size_t row = (size_t)b * S_LEN + q0 + (hi << 2) + j;
            oh[row * EDIM + h * 64 + (dt << 4) + lo] = bf16rn(oacc[dt][j]);
        }
    }
}

// ---------------------------------------------------------------------------
extern "C" void kernel_launch(void* const* d_in, const int* in_sizes, int n_in,
                              void* d_out, int out_size, void* d_ws, size_t ws_size,
                              hipStream_t stream)
{
    const float* x    = (const float*)d_in[0];
    const float* Wqkv = (const float*)d_in[1];
    const float* bqkv = (const float*)d_in[2];
    const float* Wout = (const float*)d_in[3];
    const float* bout = (const float*)d_in[4];

    float* o_out    = (float*)d_out;
    float* attn_out = o_out + (size_t)NBATCH * S_LEN * DDIM;

    const size_t nQKV = (size_t)NBATCH * S_LEN * E3;
    const size_t nO   = (size_t)NBATCH * S_LEN * EDIM;
    const size_t nWq  = (size_t)DDIM * E3;
    const size_t nWo  = (size_t)EDIM * DDIM;

    ushort* qh    = (ushort*)d_ws;        // qkv bf16
    ushort* oh    = qh + nQKV;            // o-head bf16 (xh overlay before attn)
    ushort* wqt_h = oh + nO;
    ushort* wot_h = wqt_h + nWq;

    ushort* xh = oh;   // x bf16, dead after gemm1

    const int M = NBATCH * S_LEN;  // 4096

    cast_plane<<<(int)(nO / 1024), 256, 0, stream>>>(x, xh, (int)nO);
    transpose_cast<<<dim3(E3 / 32, DDIM / 32), 256, 0, stream>>>(Wqkv, wqt_h, DDIM, E3);
    transpose_cast<<<dim3(DDIM / 32, EDIM / 32), 256, 0, stream>>>(Wout, wot_h, EDIM, DDIM);

    // K1: qkv = x @ Wqkv + bqkv (bf16, Q pre-scaled 0.125)
    gemm_bf16<0><<<dim3(E3 / 128, M / 128), 512, 0, stream>>>(
        xh, wqt_h, bqkv, nullptr, qh, M, E3, DDIM);

    // K2: fused attention
    attn_fused<<<(S_LEN / 128) * NBATCH * NHEAD, 512, 0, stream>>>(
        qh, attn_out, oh);

    // K3: o = o_head @ Wout + bout (bf16, f32 out)
    gemm_bf16<1><<<dim3(DDIM / 128, M / 128), 512, 0, stream>>>(
        oh, wot_h, bout, o_out, nullptr, M, DDIM, EDIM);
}

// Round 11
// 299.370 us; speedup vs baseline: 1.5159x; 1.0038x over previous
//
#include <hip/hip_runtime.h>
#include <cstdint>

#define S_LEN 2048
#define NBATCH 2
#define NHEAD 16
#define E3 3072
#define EDIM 1024
#define DDIM 1024

typedef __attribute__((ext_vector_type(8))) short bf8;
typedef __attribute__((ext_vector_type(4))) float f4;

#define MFMA16(A, B, C) __builtin_amdgcn_mfma_f32_16x16x32_bf16(A, B, C, 0, 0, 0)

__device__ __forceinline__ ushort bf16rn(float f) {
    unsigned u = __builtin_bit_cast(unsigned, f);
    return (ushort)((u + 0x7fffu + ((u >> 16) & 1u)) >> 16);
}

// global -> LDS direct DMA, 16B per lane (linear dest; source pre-swizzled).
__device__ __forceinline__ void gload_lds16(const ushort* g, ushort* l) {
    __builtin_amdgcn_global_load_lds(
        (const __attribute__((address_space(1))) void*)g,
        (__attribute__((address_space(3))) void*)l, 16, 0, 0);
}

// ---------------------------------------------------------------------------
// Prep 1: cast f32 -> bf16 plane (RN).
// ---------------------------------------------------------------------------
__global__ __launch_bounds__(256) void cast_plane(
    const float* __restrict__ X, ushort* __restrict__ Xh, int n)
{
    const int i = (blockIdx.x * 256 + threadIdx.x) * 4;
    if (i >= n) return;
    float4 v = *(const float4*)&X[i];
    ushort4 h;
    h.x = bf16rn(v.x); h.y = bf16rn(v.y); h.z = bf16rn(v.z); h.w = bf16rn(v.w);
    *(ushort4*)&Xh[i] = h;
}

// ---------------------------------------------------------------------------
// Prep 2: W [K][N] f32 -> transposed bf16 plane [N][K].
// ---------------------------------------------------------------------------
__global__ __launch_bounds__(256) void transpose_cast(
    const float* __restrict__ W, ushort* __restrict__ Th, int K, int N)
{
    __shared__ float tile[32][33];
    const int t  = threadIdx.x;
    const int n0 = blockIdx.x << 5, k0 = blockIdx.y << 5;
    const int c  = t & 31, r = t >> 5;
    #pragma unroll
    for (int i = 0; i < 4; ++i)
        tile[c][r + (i << 3)] = W[(size_t)(k0 + r + (i << 3)) * N + n0 + c];
    __syncthreads();
    #pragma unroll
    for (int i = 0; i < 4; ++i)
        Th[(size_t)(n0 + r + (i << 3)) * K + k0 + c] = bf16rn(tile[r + (i << 3)][c]);
}

// ---------------------------------------------------------------------------
// Plain bf16 MFMA GEMM, 128x128 tile, BK=64, 512 thr = 8 waves (2x4 of 64x32).
// global_load_lds staging with source-side XOR swizzle; XCD-chunked swizzle.
// MODE 0: C -> bf16 (bias; Q cols (c%192<64) scaled 0.125).
// MODE 1: C -> f32 nontemporal (bias).
// ---------------------------------------------------------------------------
template<int MODE>
__global__ __launch_bounds__(512, 4) void gemm_bf16(
    const ushort* __restrict__ Ah, const ushort* __restrict__ Bh,
    const float* __restrict__ bias,
    float* __restrict__ Cf, ushort* __restrict__ Ch,
    int M, int N, int K)
{
    __shared__ ushort As[128][64];
    __shared__ ushort Bs[128][64];

    const int t    = threadIdx.x;
    const int lane = t & 63;
    const int w    = t >> 6;
    const int lo   = lane & 15, hi = lane >> 4;
    const int wr   = w >> 2;
    const int wc   = w & 3;

    const int nwg  = gridDim.x * gridDim.y;
    const int orig = blockIdx.x + blockIdx.y * gridDim.x;
    const int wgid = (orig & 7) * (nwg >> 3) + (orig >> 3);
    const int rb   = (wgid / gridDim.x) << 7;
    const int cb   = (wgid % gridDim.x) << 7;

    const int lrow = lane >> 3;
    const int scol = ((lane & 7) ^ lrow) << 3;
    const int w8   = w << 1;
    const int rsw  = (lo & 7) << 3;

    f4 acc[4][2] = {};

    for (int k0 = 0; k0 < K; k0 += 64) {
        __syncthreads();
        #pragma unroll
        for (int i = 0; i < 2; ++i) {
            const int r0  = (w8 + i) << 3;
            const int row = r0 + lrow;
            gload_lds16(&Ah[(size_t)(rb + row) * K + k0 + scol], &As[r0][0]);
            gload_lds16(&Bh[(size_t)(cb + row) * K + k0 + scol], &Bs[r0][0]);
        }
        __syncthreads();

        __builtin_amdgcn_s_setprio(1);
        #pragma unroll
        for (int st = 0; st < 2; ++st) {
            const int kc = ((st << 5) + (hi << 3)) ^ rsw;
            bf8 a[4], bfr[2];
            #pragma unroll
            for (int f = 0; f < 4; ++f)
                a[f] = *(const bf8*)&As[(wr << 6) + (f << 4) + lo][kc];
            #pragma unroll
            for (int g = 0; g < 2; ++g)
                bfr[g] = *(const bf8*)&Bs[(wc << 5) + (g << 4) + lo][kc];
            #pragma unroll
            for (int f = 0; f < 4; ++f)
                #pragma unroll
                for (int g = 0; g < 2; ++g)
                    acc[f][g] = MFMA16(a[f], bfr[g], acc[f][g]);
        }
        __builtin_amdgcn_s_setprio(0);
    }

    #pragma unroll
    for (int f = 0; f < 4; ++f) {
        #pragma unroll
        for (int g = 0; g < 2; ++g) {
            const int c  = cb + (wc << 5) + (g << 4) + lo;
            const float bv = bias[c];
            const float qs = (MODE == 0 && (c % 192) < 64) ? 0.125f : 1.0f;
            #pragma unroll
            for (int j = 0; j < 4; ++j) {
                const size_t row = (size_t)rb + (wr << 6) + (f << 4) + (hi << 2) + j;
                float v = (acc[f][g][j] + bv) * qs;
                if constexpr (MODE == 0) {
                    Ch[row * N + c] = bf16rn(v);
                } else {
                    __builtin_nontemporal_store(v, &Cf[row * N + c]);
                }
            }
        }
    }
}

// ---------------------------------------------------------------------------
// Fused attention, single-bf16 QK^T, double-buffered single-barrier pipeline:
// per tile: issue K-prefetch (global_load_lds -> buf^1) and V-reg loads early,
// compute current tile (QK^T, exp, attn store, PV), ds_write V -> buf^1,
// ONE __syncthreads(). K/V load latency hides under compute.
// 1-D grid, id = qblk*32 + bh => XCD = bh%8 (K/V L2 affinity).
// ---------------------------------------------------------------------------
__global__ __launch_bounds__(512) void attn_fused(
    const ushort* __restrict__ qh,
    float* __restrict__ attn, ushort* __restrict__ oh)
{
    __shared__ ushort ksh_h[2][64][64];
    __shared__ ushort vth[2][64][72];    // V^T: [d][k]
    __shared__ ushort plds[8][16][72];   // per-wave p: [q][k]

    const int t    = threadIdx.x;
    const int lane = t & 63;
    const int wv   = t >> 6;
    const int lo   = lane & 15, hi = lane >> 4;
    const int bh   = blockIdx.x & 31;          // XCD affinity: bh%8
    const int qblk = blockIdx.x >> 5;
    const int b    = bh >> 4, h = bh & 15;
    const size_t base = (size_t)b * S_LEN * E3 + h * 192;
    const int q0   = (qblk << 7) + (wv << 4);

    const int lrow = lane >> 3;
    const int scol = ((lane & 7) ^ lrow) << 3;
    const int r0k  = wv << 3;
    const int rsw  = (lo & 7) << 3;
    const int vd   = t & 63;

    bf8 qfh[2];
    #pragma unroll
    for (int st = 0; st < 2; ++st) {
        const size_t off = base + (size_t)(q0 + lo) * E3 + (st << 5) + (hi << 3);
        qfh[st] = *(const bf8*)&qh[off];
    }

    ushort4 vr[2];

    auto issueK = [&](int kt, int buf) {
        const size_t g = base + 64 + (size_t)(kt + r0k + lrow) * E3 + scol;
        gload_lds16(&qh[g], &ksh_h[buf][r0k][0]);
    };
    auto loadV = [&](int kt) {
        #pragma unroll
        for (int i = 0; i < 2; ++i) {
            const int k4 = ((t >> 6) + (i << 3)) << 2;
            ushort4 v;
            #pragma unroll
            for (int m = 0; m < 4; ++m)
                ((ushort*)&v)[m] = qh[base + 128 + (size_t)(kt + k4 + m) * E3 + vd];
            vr[i] = v;
        }
    };
    auto writeV = [&](int buf) {
        #pragma unroll
        for (int i = 0; i < 2; ++i)
            *(ushort4*)&vth[buf][vd][((t >> 6) + (i << 3)) << 2] = vr[i];
    };

    // ---- pass 1: denominators (K double-buffered, one barrier/tile)
    issueK(0, 0);
    __syncthreads();
    float ssum = 0.0f;
    for (int kt = 0; kt < S_LEN; kt += 64) {
        const int buf = (kt >> 6) & 1;
        if (kt + 64 < S_LEN) issueK(kt + 64, buf ^ 1);
        __builtin_amdgcn_s_setprio(1);
        #pragma unroll
        for (int sub = 0; sub < 4; ++sub) {
            f4 acc = {};
            #pragma unroll
            for (int st = 0; st < 2; ++st) {
                const int kc = ((st << 5) + (hi << 3)) ^ rsw;
                bf8 kh = *(const bf8*)&ksh_h[buf][(sub << 4) + lo][kc];
                acc = MFMA16(kh, qfh[st], acc);
            }
            #pragma unroll
            for (int j = 0; j < 4; ++j) ssum += __expf(acc[j]);
        }
        __builtin_amdgcn_s_setprio(0);
        __syncthreads();
    }
    ssum += __shfl_xor(ssum, 16, 64);
    ssum += __shfl_xor(ssum, 32, 64);
    const float inv_s = 1.0f / ssum;

    // ---- pass 2: attention write + PV (K+V double-buffered)
    issueK(0, 0);
    loadV(0);
    writeV(0);
    __syncthreads();
    f4 oacc[4] = {};
    for (int kt = 0; kt < S_LEN; kt += 64) {
        const int buf = (kt >> 6) & 1;
        const bool pf = (kt + 64 < S_LEN);
        if (pf) { issueK(kt + 64, buf ^ 1); loadV(kt + 64); }

        #pragma unroll
        for (int sub = 0; sub < 4; ++sub) {
            f4 acc = {};
            __builtin_amdgcn_s_setprio(1);
            #pragma unroll
            for (int st = 0; st < 2; ++st) {
                const int kc = ((st << 5) + (hi << 3)) ^ rsw;
                bf8 kh = *(const bf8*)&ksh_h[buf][(sub << 4) + lo][kc];
                acc = MFMA16(kh, qfh[st], acc);
            }
            __builtin_amdgcn_s_setprio(0);
            f4 pw; ushort4 pb;
            #pragma unroll
            for (int j = 0; j < 4; ++j) {
                float p = __expf(acc[j]) * inv_s;
                pw[j] = p;
                ((ushort*)&pb)[j] = bf16rn(p);
            }
            __builtin_nontemporal_store(pw,
                (f4*)&attn[((size_t)bh * S_LEN + q0 + lo) * S_LEN +
                           kt + (sub << 4) + (hi << 2)]);
            *(ushort4*)&plds[wv][lo][(sub << 4) + (hi << 2)] = pb;
        }
        // PV: o += p @ V
        __builtin_amdgcn_s_setprio(1);
        #pragma unroll
        for (int kk = 0; kk < 2; ++kk) {
            bf8 pa = *(const bf8*)&plds[wv][lo][(kk << 5) + (hi << 3)];
            #pragma unroll
            for (int dt = 0; dt < 4; ++dt) {
                bf8 vb = *(const bf8*)&vth[buf][(dt << 4) + lo][(kk << 5) + (hi << 3)];
                oacc[dt] = MFMA16(pa, vb, oacc[dt]);
            }
        }
        __builtin_amdgcn_s_setprio(0);
        if (pf) writeV(buf ^ 1);
        __syncthreads();
    }

    // epilogue: o head -> bf16
    #pragma unroll
    for (int dt = 0; dt < 4; ++dt) {
        #pragma unroll
        for (int j = 0; j < 4; ++j) {
            const size_t row = (size_t)b * S_LEN + q0 + (hi << 2) + j;
            oh[row * EDIM + h * 64 + (dt << 4) + lo] = bf16rn(oacc[dt][j]);
        }
    }
}

// ---------------------------------------------------------------------------
extern "C" void kernel_launch(void* const* d_in, const int* in_sizes, int n_in,
                              void* d_out, int out_size, void* d_ws, size_t ws_size,
                              hipStream_t stream)
{
    const float* x    = (const float*)d_in[0];
    const float* Wqkv = (const float*)d_in[1];
    const float* bqkv = (const float*)d_in[2];
    const float* Wout = (const float*)d_in[3];
    const float* bout = (const float*)d_in[4];

    float* o_out    = (float*)d_out;
    float* attn_out = o_out + (size_t)NBATCH * S_LEN * DDIM;

    const size_t nQKV = (size_t)NBATCH * S_LEN * E3;
    const size_t nO   = (size_t)NBATCH * S_LEN * EDIM;
    const size_t nWq  = (size_t)DDIM * E3;

    ushort* qh    = (ushort*)d_ws;        // qkv bf16
    ushort* oh    = qh + nQKV;            // o-head bf16 (xh overlay before attn)
    ushort* wqt_h = oh + nO;
    ushort* wot_h = wqt_h + nWq;

    ushort* xh = oh;   // x bf16, dead after gemm1

    const int M = NBATCH * S_LEN;  // 4096

    cast_plane<<<(int)(nO / 1024), 256, 0, stream>>>(x, xh, (int)nO);
    transpose_cast<<<dim3(E3 / 32, DDIM / 32), 256, 0, stream>>>(Wqkv, wqt_h, DDIM, E3);
    transpose_cast<<<dim3(DDIM / 32, EDIM / 32), 256, 0, stream>>>(Wout, wot_h, EDIM, DDIM);

    // K1: qkv = x @ Wqkv + bqkv (bf16, Q pre-scaled 0.125)
    gemm_bf16<0><<<dim3(E3 / 128, M / 128), 512, 0, stream>>>(
        xh, wqt_h, bqkv, nullptr, qh, M, E3, DDIM);

    // K2: fused attention
    attn_fused<<<(S_LEN / 128) * NBATCH * NHEAD, 512, 0, stream>>>(
        qh, attn_out, oh);

    // K3: o = o_head @ Wout + bout (bf16, f32 out)
    gemm_bf16<1><<<dim3(DDIM / 128, M / 128), 512, 0, stream>>>(
        oh, wot_h, bout, o_out, nullptr, M, DDIM, EDIM);
}